// Round 8
// baseline (188.552 us; speedup 1.0000x reference)
//
#include <hip/hip_runtime.h>
#include <hip/hip_bf16.h>
#include <stdint.h>

#define IN_C 128
#define HID_C 128
#define OUT_C 64

#define NBUCK 256
#define BSH 9
#define EPB 8192

typedef _Float16 h8 __attribute__((ext_vector_type(8)));
typedef _Float16 h2 __attribute__((ext_vector_type(2)));
typedef float f4 __attribute__((ext_vector_type(4)));
typedef float f2 __attribute__((ext_vector_type(2)));
typedef unsigned u4 __attribute__((ext_vector_type(4)));

__device__ inline float h2lo(unsigned v){ h2 t = __builtin_bit_cast(h2, v); return (float)t[0]; }
__device__ inline float h2hi(unsigned v){ h2 t = __builtin_bit_cast(h2, v); return (float)t[1]; }
__device__ inline unsigned packh2(float a, float b){ h2 t; t[0]=(_Float16)a; t[1]=(_Float16)b; return __builtin_bit_cast(unsigned, t); }

// ---------------- weight packing helper ----------------
__device__ inline void pack_one(const float* __restrict__ W, int C, _Float16* __restrict__ outp, int tid){
    int l = tid & 63;
    int f = tid >> 6;
    int NJT = C / 16;
    int kt = f / NJT;
    int jt = f - kt*NJT;
    int kbase = kt*32 + (l >> 4)*8;
    int col   = jt*16 + (l & 15);
    h8 o;
    #pragma unroll
    for (int r = 0; r < 8; ++r) o[r] = (_Float16)W[(kbase + r)*C + col];
    ((h8*)outp)[f*64 + l] = o;
}

// ---------------- front: hist (blocks [0,NBLK)) || pack (NBLK..NBLK+24) || cvt (rest) ----------------
__global__ __launch_bounds__(256) void k_front(const int* __restrict__ dst, int E, int NBLK,
                                               int* __restrict__ histT,
                                               const float* __restrict__ x, h8* __restrict__ xh,
                                               uint2* __restrict__ x8, int n8,
                                               const float* __restrict__ Wl1, const float* __restrict__ Wr1,
                                               const float* __restrict__ Wl2, const float* __restrict__ Wr2,
                                               _Float16* __restrict__ wl1p, _Float16* __restrict__ wr1p,
                                               _Float16* __restrict__ wl2p, _Float16* __restrict__ wr2p){
    __shared__ int h[NBUCK];
    int bid = blockIdx.x, t = threadIdx.x;
    if (bid < NBLK){
        h[t] = 0; __syncthreads();
        int e0 = bid*EPB, e1 = min(E, e0 + EPB);
        for (int e = e0 + t; e < e1; e += 256) atomicAdd(&h[((unsigned)dst[e]) >> BSH], 1);
        __syncthreads();
        histT[t*NBLK + bid] = h[t];
    } else if (bid < NBLK + 24){
        int tid = (bid - NBLK)*256 + t;
        if (tid < 2048)        pack_one(Wl1, 128, wl1p, tid);
        else if (tid < 4096)   pack_one(Wr1, 128, wr1p, tid - 2048);
        else if (tid < 5120)   pack_one(Wl2,  64, wl2p, tid - 4096);
        else if (tid < 6144)   pack_one(Wr2,  64, wr2p, tid - 5120);
    } else {
        int g = (bid - NBLK - 24)*256 + t;
        if (g < n8){
            const f4* xp = (const f4*)(x + (size_t)g*8);
            f4 a = xp[0], b = xp[1];
            h8 o;
            o[0]=(_Float16)a[0]; o[1]=(_Float16)a[1]; o[2]=(_Float16)a[2]; o[3]=(_Float16)a[3];
            o[4]=(_Float16)b[0]; o[5]=(_Float16)b[1]; o[6]=(_Float16)b[2]; o[7]=(_Float16)b[3];
            xh[g] = o;
            int w0 = __builtin_amdgcn_cvt_pk_fp8_f32(a[0], a[1], 0, false);
            w0     = __builtin_amdgcn_cvt_pk_fp8_f32(a[2], a[3], w0, true);
            int w1 = __builtin_amdgcn_cvt_pk_fp8_f32(b[0], b[1], 0, false);
            w1     = __builtin_amdgcn_cvt_pk_fp8_f32(b[2], b[3], w1, true);
            uint2 p; p.x = (unsigned)w0; p.y = (unsigned)w1;
            x8[g] = p;
        }
    }
}

__global__ void k_scanA(const int* __restrict__ cnt, int* __restrict__ tmp, int* __restrict__ bsum, int n){
    __shared__ int s[256];
    int t = threadIdx.x, g = blockIdx.x*256 + t;
    int v = (g < n) ? cnt[g] : 0;
    s[t] = v; __syncthreads();
    for (int off = 1; off < 256; off <<= 1){
        int a = (t >= off) ? s[t-off] : 0;
        __syncthreads();
        s[t] += a;
        __syncthreads();
    }
    int excl = (t == 0) ? 0 : s[t-1];
    if (g < n) tmp[g] = excl;
    if (t == 255) bsum[blockIdx.x] = s[255];
}

__global__ void k_scanB(int* __restrict__ bsum, int nb){
    __shared__ int s[256];
    int t = threadIdx.x;
    int v = (t < nb) ? bsum[t] : 0;
    s[t] = v; __syncthreads();
    for (int off = 1; off < 256; off <<= 1){
        int a = (t >= off) ? s[t-off] : 0;
        __syncthreads();
        s[t] += a;
        __syncthreads();
    }
    int excl = (t == 0) ? 0 : s[t-1];
    if (t < nb) bsum[t] = excl;
}

// S[g] = tmp[g] + bsum[g>>8], computed on the fly
__global__ __launch_bounds__(256) void k_scatter(const int* __restrict__ src, const int* __restrict__ dst,
                                                 int E, const int* __restrict__ tmp, const int* __restrict__ bsum,
                                                 int NBLK, unsigned* __restrict__ sorted){
    __shared__ int off[NBUCK];
    int t = threadIdx.x;
    int g = t*NBLK + blockIdx.x;
    off[t] = tmp[g] + bsum[g >> 8];
    __syncthreads();
    int e0 = blockIdx.x*EPB, e1 = min(E, e0 + EPB);
    for (int e = e0 + t; e < e1; e += 256){
        int d = dst[e];
        int b = ((unsigned)d) >> BSH;
        int p = atomicAdd(&off[b], 1);
        sorted[p] = (unsigned)src[e] | (((unsigned)(d & ((1<<BSH)-1))) << 17);
    }
}

__global__ __launch_bounds__(512) void k_csr(const unsigned* __restrict__ sorted,
                                             const int* __restrict__ tmp, const int* __restrict__ bsum,
                                             int NBLK, int E, int N,
                                             int* __restrict__ csr, int* __restrict__ row_start){
    __shared__ int cnt[512];
    __shared__ int sc[512];
    int b = blockIdx.x, t = threadIdx.x;
    int i0 = b*NBLK;
    int bs = tmp[i0] + bsum[i0 >> 8];
    int be = (b == NBUCK-1) ? E : (tmp[i0 + NBLK] + bsum[(i0 + NBLK) >> 8]);
    cnt[t] = 0; __syncthreads();
    for (int e = bs + t; e < be; e += 512) atomicAdd(&cnt[sorted[e] >> 17], 1);
    __syncthreads();
    sc[t] = cnt[t]; __syncthreads();
    for (int off = 1; off < 512; off <<= 1){
        int a = (t >= off) ? sc[t-off] : 0;
        __syncthreads();
        sc[t] += a;
        __syncthreads();
    }
    int excl = sc[t] - cnt[t];
    int nid = (b << BSH) + t;
    if (nid < N) row_start[nid] = bs + excl;
    if (t == 0 && b == (N >> BSH)) row_start[N] = E;
    __syncthreads();
    cnt[t] = excl;
    __syncthreads();
    for (int e = bs + t; e < be; e += 512){
        unsigned v = sorted[e];
        int dl = v >> 17;
        int p = atomicAdd(&cnt[dl], 1);
        csr[bs + p] = (int)(v & 0x1FFFFu);
    }
}

// ---------------- aggregation 1: whole wave per node (4 nodes sequential); e4=lane>>4 edge slot, c=lane&15 uint2 col ----------------
__global__ __launch_bounds__(256) void k_agg1(const int* __restrict__ row_start, const int* __restrict__ csr,
                                              const uint2* __restrict__ x8, unsigned* __restrict__ mh32, int n){
    int wave = (int)((blockIdx.x*(unsigned)blockDim.x + threadIdx.x) >> 6);
    int lane = threadIdx.x & 63;
    int e4 = lane >> 4, c = lane & 15;
    int n0 = wave*4;
    if (n0 >= n) return;
    #pragma unroll 1
    for (int k = 0; k < 4; ++k){
        int node = n0 + k;
        if (node >= n) break;
        int base = row_start[node], end = row_start[node+1];
        int deg = end - base;
        f2 a0={0.f,0.f},a1={0.f,0.f},a2={0.f,0.f},a3={0.f,0.f};
        f2 b0={0.f,0.f},b1={0.f,0.f},b2={0.f,0.f},b3={0.f,0.f};
        int i = base;
        for (; i + 8 <= end; i += 8){
            int ea = csr[i + e4];
            int eb = csr[i + 4 + e4];
            uint2 va = x8[(size_t)ea*16 + c];
            uint2 vb = x8[(size_t)eb*16 + c];
            a0 += __builtin_amdgcn_cvt_pk_f32_fp8(va.x, false);
            a1 += __builtin_amdgcn_cvt_pk_f32_fp8(va.x, true);
            a2 += __builtin_amdgcn_cvt_pk_f32_fp8(va.y, false);
            a3 += __builtin_amdgcn_cvt_pk_f32_fp8(va.y, true);
            b0 += __builtin_amdgcn_cvt_pk_f32_fp8(vb.x, false);
            b1 += __builtin_amdgcn_cvt_pk_f32_fp8(vb.x, true);
            b2 += __builtin_amdgcn_cvt_pk_f32_fp8(vb.y, false);
            b3 += __builtin_amdgcn_cvt_pk_f32_fp8(vb.y, true);
        }
        for (; i < end; i += 4){
            if (i + e4 < end){
                int e = csr[i + e4];
                uint2 v = x8[(size_t)e*16 + c];
                a0 += __builtin_amdgcn_cvt_pk_f32_fp8(v.x, false);
                a1 += __builtin_amdgcn_cvt_pk_f32_fp8(v.x, true);
                a2 += __builtin_amdgcn_cvt_pk_f32_fp8(v.y, false);
                a3 += __builtin_amdgcn_cvt_pk_f32_fp8(v.y, true);
            }
        }
        a0 += b0; a1 += b1; a2 += b2; a3 += b3;
        // reduce across edge slots (lanes xor 16, 32)
        a0[0] += __shfl_xor(a0[0], 16); a0[1] += __shfl_xor(a0[1], 16);
        a1[0] += __shfl_xor(a1[0], 16); a1[1] += __shfl_xor(a1[1], 16);
        a2[0] += __shfl_xor(a2[0], 16); a2[1] += __shfl_xor(a2[1], 16);
        a3[0] += __shfl_xor(a3[0], 16); a3[1] += __shfl_xor(a3[1], 16);
        a0[0] += __shfl_xor(a0[0], 32); a0[1] += __shfl_xor(a0[1], 32);
        a1[0] += __shfl_xor(a1[0], 32); a1[1] += __shfl_xor(a1[1], 32);
        a2[0] += __shfl_xor(a2[0], 32); a2[1] += __shfl_xor(a2[1], 32);
        a3[0] += __shfl_xor(a3[0], 32); a3[1] += __shfl_xor(a3[1], 32);
        if (e4 == 0){
            float sc = 1.0f / (float)max(deg, 1);
            u4 o;
            o[0] = packh2(a0[0]*sc, a0[1]*sc);
            o[1] = packh2(a1[0]*sc, a1[1]*sc);
            o[2] = packh2(a2[0]*sc, a2[1]*sc);
            o[3] = packh2(a3[0]*sc, a3[1]*sc);
            *(u4*)(mh32 + (size_t)node*64 + 4*c) = o;
        }
    }
}

// ---------------- fused GEMM: layer-1 weights LDS-staged; H^T in-register; layer 2 fused; P,Q out fp8/fp16 ----------------
__global__ __launch_bounds__(256, 2) void k_gemm_fused(
    const _Float16* __restrict__ A0,   // m1h [M][128] f16
    const _Float16* __restrict__ A1,   // xh  [M][128] f16
    const h8* __restrict__ B0,         // wl1p frags (2048 h8)
    const h8* __restrict__ B1,         // wr1p frags (2048 h8)
    const float* __restrict__ bias1,
    const h8* __restrict__ W2l,        // wl2p frags
    const h8* __restrict__ W2r,        // wr2p frags
    const float* __restrict__ bias2,
    unsigned* __restrict__ P8,         // [M][16] u32 (64 fp8)
    uint2* __restrict__ Qh,            // [M][16] uint2 (64 f16)
    int M)
{
    __shared__ h8 shB[4096];           // 64 KB
    int tid = threadIdx.x;
    #pragma unroll
    for (int i = 0; i < 8; ++i) shB[i*256 + tid] = B0[i*256 + tid];
    #pragma unroll
    for (int i = 0; i < 8; ++i) shB[2048 + i*256 + tid] = B1[i*256 + tid];
    __syncthreads();

    int wid = tid >> 6, lane = tid & 63;
    int m0 = (blockIdx.x*4 + wid) * 16;
    if (m0 >= M) return;
    int m = lane & 15, kg = lane >> 4;
    int rowc = min(m0 + m, M-1);

    f4 acc[8];
    #pragma unroll
    for (int j = 0; j < 8; ++j) acc[j] = (f4)0.0f;

    #pragma unroll
    for (int ph = 0; ph < 2; ++ph){
        const _Float16* A = ph ? A1 : A0;
        #pragma unroll
        for (int kt = 0; kt < 4; ++kt){
            h8 nf = *(const h8*)(A + (size_t)rowc*128 + kt*32 + kg*8);
            #pragma unroll
            for (int j = 0; j < 8; ++j){
                h8 wf = shB[ph*2048 + (kt*8 + j)*64 + lane];
                acc[j] = __builtin_amdgcn_mfma_f32_16x16x32_f16(wf, nf, acc[j], 0, 0, 0);
            }
        }
    }

    unsigned hreg[16];
    #pragma unroll
    for (int j = 0; j < 8; ++j){
        f4 bb = *(const f4*)(bias1 + j*16 + kg*4);
        float v0 = acc[j][0] + bb[0]; v0 = v0 > 0.f ? v0 : 0.f;
        float v1 = acc[j][1] + bb[1]; v1 = v1 > 0.f ? v1 : 0.f;
        float v2 = acc[j][2] + bb[2]; v2 = v2 > 0.f ? v2 : 0.f;
        float v3 = acc[j][3] + bb[3]; v3 = v3 > 0.f ? v3 : 0.f;
        hreg[2*j]   = packh2(v0, v1);
        hreg[2*j+1] = packh2(v2, v3);
    }

    f4 accP[4], accQ[4];
    #pragma unroll
    for (int j = 0; j < 4; ++j){ accP[j] = (f4)0.0f; accQ[j] = (f4)0.0f; }

    int srcA = ((kg & 1) * 2) * 16 + m;
    int srcB = srcA + 16;
    bool hi = (kg >> 1) & 1;

    #pragma unroll
    for (int kt = 0; kt < 4; ++kt){
        unsigned sA0 = (unsigned)__shfl((int)hreg[4*kt+0], srcA, 64);
        unsigned sA1 = (unsigned)__shfl((int)hreg[4*kt+1], srcA, 64);
        unsigned sA2 = (unsigned)__shfl((int)hreg[4*kt+2], srcA, 64);
        unsigned sA3 = (unsigned)__shfl((int)hreg[4*kt+3], srcA, 64);
        unsigned sB0 = (unsigned)__shfl((int)hreg[4*kt+0], srcB, 64);
        unsigned sB1 = (unsigned)__shfl((int)hreg[4*kt+1], srcB, 64);
        unsigned sB2 = (unsigned)__shfl((int)hreg[4*kt+2], srcB, 64);
        unsigned sB3 = (unsigned)__shfl((int)hreg[4*kt+3], srcB, 64);
        u4 u;
        u[0] = hi ? sA2 : sA0;
        u[1] = hi ? sA3 : sA1;
        u[2] = hi ? sB2 : sB0;
        u[3] = hi ? sB3 : sB1;
        h8 hf = __builtin_bit_cast(h8, u);
        #pragma unroll
        for (int j2 = 0; j2 < 4; ++j2){
            accP[j2] = __builtin_amdgcn_mfma_f32_16x16x32_f16(W2l[(kt*4 + j2)*64 + lane], hf, accP[j2], 0, 0, 0);
            accQ[j2] = __builtin_amdgcn_mfma_f32_16x16x32_f16(W2r[(kt*4 + j2)*64 + lane], hf, accQ[j2], 0, 0, 0);
        }
    }

    int node = m0 + m;
    if (node < M){
        #pragma unroll
        for (int j2 = 0; j2 < 4; ++j2){
            int f = j2*16 + kg*4;
            int p8 = __builtin_amdgcn_cvt_pk_fp8_f32(accP[j2][0], accP[j2][1], 0, false);
            p8     = __builtin_amdgcn_cvt_pk_fp8_f32(accP[j2][2], accP[j2][3], p8, true);
            P8[(size_t)node*16 + j2*4 + kg] = (unsigned)p8;
            f4 bb2 = *(const f4*)(bias2 + f);
            uint2 qp;
            qp.x = packh2(accQ[j2][0] + bb2[0], accQ[j2][1] + bb2[1]);
            qp.y = packh2(accQ[j2][2] + bb2[2], accQ[j2][3] + bb2[3]);
            Qh[(size_t)node*16 + j2*4 + kg] = qp;
        }
    }
}

// ---------------- aggregation 2: out = Qh + mean-gather(P8); whole wave per node (4 sequential) ----------------
__global__ __launch_bounds__(256) void k_agg2f(const int* __restrict__ row_start, const int* __restrict__ csr,
                                               const unsigned* __restrict__ p8, const uint2* __restrict__ Qh,
                                               float* __restrict__ out, int n){
    int wave = (int)((blockIdx.x*(unsigned)blockDim.x + threadIdx.x) >> 6);
    int lane = threadIdx.x & 63;
    int e4 = lane >> 4, c = lane & 15;
    int n0 = wave*4;
    if (n0 >= n) return;
    #pragma unroll 1
    for (int k = 0; k < 4; ++k){
        int node = n0 + k;
        if (node >= n) break;
        int base = row_start[node], end = row_start[node+1];
        int deg = end - base;
        f2 a0={0.f,0.f}, a1={0.f,0.f}, b0={0.f,0.f}, b1={0.f,0.f};
        int i = base;
        for (; i + 8 <= end; i += 8){
            int ea = csr[i + e4];
            int eb = csr[i + 4 + e4];
            unsigned va = p8[(size_t)ea*16 + c];
            unsigned vb = p8[(size_t)eb*16 + c];
            a0 += __builtin_amdgcn_cvt_pk_f32_fp8(va, false);
            a1 += __builtin_amdgcn_cvt_pk_f32_fp8(va, true);
            b0 += __builtin_amdgcn_cvt_pk_f32_fp8(vb, false);
            b1 += __builtin_amdgcn_cvt_pk_f32_fp8(vb, true);
        }
        for (; i < end; i += 4){
            if (i + e4 < end){
                int e = csr[i + e4];
                unsigned v = p8[(size_t)e*16 + c];
                a0 += __builtin_amdgcn_cvt_pk_f32_fp8(v, false);
                a1 += __builtin_amdgcn_cvt_pk_f32_fp8(v, true);
            }
        }
        a0 += b0; a1 += b1;
        a0[0] += __shfl_xor(a0[0], 16); a0[1] += __shfl_xor(a0[1], 16);
        a1[0] += __shfl_xor(a1[0], 16); a1[1] += __shfl_xor(a1[1], 16);
        a0[0] += __shfl_xor(a0[0], 32); a0[1] += __shfl_xor(a0[1], 32);
        a1[0] += __shfl_xor(a1[0], 32); a1[1] += __shfl_xor(a1[1], 32);
        if (e4 == 0){
            float sc = 1.0f / (float)max(deg, 1);
            uint2 qh = Qh[(size_t)node*16 + c];
            f4 o;
            o[0] = a0[0]*sc + h2lo(qh.x);
            o[1] = a0[1]*sc + h2hi(qh.x);
            o[2] = a1[0]*sc + h2lo(qh.y);
            o[3] = a1[1]*sc + h2hi(qh.y);
            *(f4*)(out + (size_t)node*64 + 4*c) = o;
        }
    }
}

extern "C" void kernel_launch(void* const* d_in, const int* in_sizes, int n_in,
                              void* d_out, int out_size, void* d_ws, size_t ws_size,
                              hipStream_t stream) {
    const float* x   = (const float*)d_in[0];
    const int*   ei  = (const int*)d_in[1];
    const float* Wl1 = (const float*)d_in[2];
    const float* bl1 = (const float*)d_in[3];
    const float* Wr1 = (const float*)d_in[4];
    const float* Wl2 = (const float*)d_in[5];
    const float* bl2 = (const float*)d_in[6];
    const float* Wr2 = (const float*)d_in[7];

    const int N = in_sizes[0] / IN_C;
    const int E = in_sizes[1] / 2;
    const int* src = ei;
    const int* dst = ei + E;

    const int NBLK = (E + EPB - 1) / EPB;
    const int n_s  = NBUCK * NBLK;

    char* w = (char*)d_ws;
    size_t off = 0;
    auto alloc = [&](size_t bytes) -> char* {
        char* p = w + off;
        off = (off + bytes + 255) & ~(size_t)255;
        return p;
    };
    int* histT      = (int*)alloc((size_t)n_s*4);
    int* tmp        = (int*)alloc((size_t)n_s*4);
    int* bsum       = (int*)alloc(4096);
    unsigned* sorted= (unsigned*)alloc((size_t)E*4);
    int* csr        = (int*)alloc((size_t)E*4);
    int* row_start  = (int*)alloc((size_t)(N+1)*4);
    _Float16* xh    = (_Float16*)alloc((size_t)N*IN_C*2);
    unsigned* x8    = (unsigned*)alloc((size_t)N*IN_C);
    _Float16* m1h   = (_Float16*)alloc((size_t)N*IN_C*2);
    unsigned* p8    = (unsigned*)alloc((size_t)N*OUT_C);
    unsigned* qh    = (unsigned*)alloc((size_t)N*OUT_C*2);
    _Float16* wl1p  = (_Float16*)alloc(4*8*64*8*2);
    _Float16* wr1p  = (_Float16*)alloc(4*8*64*8*2);
    _Float16* wl2p  = (_Float16*)alloc(4*4*64*8*2);
    _Float16* wr2p  = (_Float16*)alloc(4*4*64*8*2);

    const int SB = (n_s + 255) / 256;
    const int n8 = N*IN_C/8;
    const int CVB = (n8 + 255)/256;

    k_front  <<<NBLK + 24 + CVB, 256, 0, stream>>>(dst, E, NBLK, histT,
                                                   x, (h8*)xh, (uint2*)x8, n8,
                                                   Wl1, Wr1, Wl2, Wr2, wl1p, wr1p, wl2p, wr2p);
    k_scanA  <<<SB, 256, 0, stream>>>(histT, tmp, bsum, n_s);
    k_scanB  <<<1, 256, 0, stream>>>(bsum, SB);
    k_scatter<<<NBLK, 256, 0, stream>>>(src, dst, E, tmp, bsum, NBLK, sorted);
    k_csr    <<<NBUCK, 512, 0, stream>>>(sorted, tmp, bsum, NBLK, E, N, csr, row_start);

    const int AGB = (N + 15) / 16;   // one wave per 4 nodes
    k_agg1<<<AGB, 256, 0, stream>>>(row_start, csr, (const uint2*)x8, (unsigned*)m1h, N);

    const int GB2 = (N + 63)/64;
    k_gemm_fused<<<GB2, 256, 0, stream>>>(m1h, xh, (const h8*)wl1p, (const h8*)wr1p, bl1,
                                          (const h8*)wl2p, (const h8*)wr2p, bl2,
                                          p8, (uint2*)qh, N);

    k_agg2f<<<AGB, 256, 0, stream>>>(row_start, csr, p8, (const uint2*)qh, (float*)d_out, N);
}

// Round 9
// 160.841 us; speedup vs baseline: 1.1723x; 1.1723x over previous
//
#include <hip/hip_runtime.h>
#include <hip/hip_bf16.h>
#include <stdint.h>

#define IN_C 128
#define HID_C 128
#define OUT_C 64

#define NBUCK 256
#define BSH 9
#define EPB 8192

typedef _Float16 h8 __attribute__((ext_vector_type(8)));
typedef _Float16 h2 __attribute__((ext_vector_type(2)));
typedef float f4 __attribute__((ext_vector_type(4)));
typedef float f2 __attribute__((ext_vector_type(2)));
typedef unsigned u4 __attribute__((ext_vector_type(4)));

__device__ inline float h2lo(unsigned v){ h2 t = __builtin_bit_cast(h2, v); return (float)t[0]; }
__device__ inline float h2hi(unsigned v){ h2 t = __builtin_bit_cast(h2, v); return (float)t[1]; }
__device__ inline unsigned packh2(float a, float b){ h2 t; t[0]=(_Float16)a; t[1]=(_Float16)b; return __builtin_bit_cast(unsigned, t); }

// ---------------- weight packing helper ----------------
__device__ inline void pack_one(const float* __restrict__ W, int C, _Float16* __restrict__ outp, int tid){
    int l = tid & 63;
    int f = tid >> 6;
    int NJT = C / 16;
    int kt = f / NJT;
    int jt = f - kt*NJT;
    int kbase = kt*32 + (l >> 4)*8;
    int col   = jt*16 + (l & 15);
    h8 o;
    #pragma unroll
    for (int r = 0; r < 8; ++r) o[r] = (_Float16)W[(kbase + r)*C + col];
    ((h8*)outp)[f*64 + l] = o;
}

// ---------------- front: hist (blocks [0,NBLK)) || pack || cvt ----------------
__global__ __launch_bounds__(256) void k_front(const int* __restrict__ dst, int E, int NBLK,
                                               int* __restrict__ histT,
                                               const float* __restrict__ x, h8* __restrict__ xh,
                                               uint2* __restrict__ x8, int n8,
                                               const float* __restrict__ Wl1, const float* __restrict__ Wr1,
                                               const float* __restrict__ Wl2, const float* __restrict__ Wr2,
                                               _Float16* __restrict__ wl1p, _Float16* __restrict__ wr1p,
                                               _Float16* __restrict__ wl2p, _Float16* __restrict__ wr2p){
    __shared__ int h[NBUCK];
    int bid = blockIdx.x, t = threadIdx.x;
    if (bid < NBLK){
        h[t] = 0; __syncthreads();
        int e0 = bid*EPB, e1 = min(E, e0 + EPB);
        for (int e = e0 + t; e < e1; e += 256) atomicAdd(&h[((unsigned)dst[e]) >> BSH], 1);
        __syncthreads();
        histT[t*NBLK + bid] = h[t];
    } else if (bid < NBLK + 24){
        int tid = (bid - NBLK)*256 + t;
        if (tid < 2048)        pack_one(Wl1, 128, wl1p, tid);
        else if (tid < 4096)   pack_one(Wr1, 128, wr1p, tid - 2048);
        else if (tid < 5120)   pack_one(Wl2,  64, wl2p, tid - 4096);
        else if (tid < 6144)   pack_one(Wr2,  64, wr2p, tid - 5120);
    } else {
        int g = (bid - NBLK - 24)*256 + t;
        if (g < n8){
            const f4* xp = (const f4*)(x + (size_t)g*8);
            f4 a = xp[0], b = xp[1];
            h8 o;
            o[0]=(_Float16)a[0]; o[1]=(_Float16)a[1]; o[2]=(_Float16)a[2]; o[3]=(_Float16)a[3];
            o[4]=(_Float16)b[0]; o[5]=(_Float16)b[1]; o[6]=(_Float16)b[2]; o[7]=(_Float16)b[3];
            xh[g] = o;
            int w0 = __builtin_amdgcn_cvt_pk_fp8_f32(a[0], a[1], 0, false);
            w0     = __builtin_amdgcn_cvt_pk_fp8_f32(a[2], a[3], w0, true);
            int w1 = __builtin_amdgcn_cvt_pk_fp8_f32(b[0], b[1], 0, false);
            w1     = __builtin_amdgcn_cvt_pk_fp8_f32(b[2], b[3], w1, true);
            uint2 p; p.x = (unsigned)w0; p.y = (unsigned)w1;
            x8[g] = p;
        }
    }
}

__global__ void k_scanA(const int* __restrict__ cnt, int* __restrict__ tmp, int* __restrict__ bsum, int n){
    __shared__ int s[256];
    int t = threadIdx.x, g = blockIdx.x*256 + t;
    int v = (g < n) ? cnt[g] : 0;
    s[t] = v; __syncthreads();
    for (int off = 1; off < 256; off <<= 1){
        int a = (t >= off) ? s[t-off] : 0;
        __syncthreads();
        s[t] += a;
        __syncthreads();
    }
    int excl = (t == 0) ? 0 : s[t-1];
    if (g < n) tmp[g] = excl;
    if (t == 255) bsum[blockIdx.x] = s[255];
}

__global__ void k_scanB(int* __restrict__ bsum, int nb){
    __shared__ int s[256];
    int t = threadIdx.x;
    int v = (t < nb) ? bsum[t] : 0;
    s[t] = v; __syncthreads();
    for (int off = 1; off < 256; off <<= 1){
        int a = (t >= off) ? s[t-off] : 0;
        __syncthreads();
        s[t] += a;
        __syncthreads();
    }
    int excl = (t == 0) ? 0 : s[t-1];
    if (t < nb) bsum[t] = excl;
}

// S[g] = tmp[g] + bsum[g>>8], computed on the fly
__global__ __launch_bounds__(256) void k_scatter(const int* __restrict__ src, const int* __restrict__ dst,
                                                 int E, const int* __restrict__ tmp, const int* __restrict__ bsum,
                                                 int NBLK, unsigned* __restrict__ sorted){
    __shared__ int off[NBUCK];
    int t = threadIdx.x;
    int g = t*NBLK + blockIdx.x;
    off[t] = tmp[g] + bsum[g >> 8];
    __syncthreads();
    int e0 = blockIdx.x*EPB, e1 = min(E, e0 + EPB);
    for (int e = e0 + t; e < e1; e += 256){
        int d = dst[e];
        int b = ((unsigned)d) >> BSH;
        int p = atomicAdd(&off[b], 1);
        sorted[p] = (unsigned)src[e] | (((unsigned)(d & ((1<<BSH)-1))) << 17);
    }
}

__global__ __launch_bounds__(512) void k_csr(const unsigned* __restrict__ sorted,
                                             const int* __restrict__ tmp, const int* __restrict__ bsum,
                                             int NBLK, int E, int N,
                                             int* __restrict__ csr, int* __restrict__ row_start){
    __shared__ int cnt[512];
    __shared__ int sc[512];
    int b = blockIdx.x, t = threadIdx.x;
    int i0 = b*NBLK;
    int bs = tmp[i0] + bsum[i0 >> 8];
    int be = (b == NBUCK-1) ? E : (tmp[i0 + NBLK] + bsum[(i0 + NBLK) >> 8]);
    cnt[t] = 0; __syncthreads();
    for (int e = bs + t; e < be; e += 512) atomicAdd(&cnt[sorted[e] >> 17], 1);
    __syncthreads();
    sc[t] = cnt[t]; __syncthreads();
    for (int off = 1; off < 512; off <<= 1){
        int a = (t >= off) ? sc[t-off] : 0;
        __syncthreads();
        sc[t] += a;
        __syncthreads();
    }
    int excl = sc[t] - cnt[t];
    int nid = (b << BSH) + t;
    if (nid < N) row_start[nid] = bs + excl;
    if (t == 0 && b == (N >> BSH)) row_start[N] = E;
    __syncthreads();
    cnt[t] = excl;
    __syncthreads();
    for (int e = bs + t; e < be; e += 512){
        unsigned v = sorted[e];
        int dl = v >> 17;
        int p = atomicAdd(&cnt[dl], 1);
        csr[bs + p] = (int)(v & 0x1FFFFu);
    }
}

// ---------------- aggregation 1: 16 lanes per node (lane c owns feats 8c..8c+7 via uint2), unroll-4 ----------------
__global__ void k_agg1(const int* __restrict__ row_start, const int* __restrict__ csr,
                       const uint2* __restrict__ x8, unsigned* __restrict__ mh32, int n){
    int node = (int)((blockIdx.x*(unsigned)blockDim.x + threadIdx.x) >> 4);
    int c = threadIdx.x & 15;
    if (node >= n) return;
    int base = row_start[node], end = row_start[node+1];
    int deg = end - base;
    f2 a0={0.f,0.f}, a1={0.f,0.f}, a2={0.f,0.f}, a3={0.f,0.f};
    f2 b0={0.f,0.f}, b1={0.f,0.f}, b2={0.f,0.f}, b3={0.f,0.f};
    int i = base;
    for (; i + 3 < end; i += 4){
        int e0 = csr[i], e1 = csr[i+1], e2 = csr[i+2], e3 = csr[i+3];
        uint2 v0 = x8[(size_t)e0*16 + c];
        uint2 v1 = x8[(size_t)e1*16 + c];
        uint2 v2 = x8[(size_t)e2*16 + c];
        uint2 v3 = x8[(size_t)e3*16 + c];
        a0 += __builtin_amdgcn_cvt_pk_f32_fp8(v0.x, false);
        a1 += __builtin_amdgcn_cvt_pk_f32_fp8(v0.x, true);
        a2 += __builtin_amdgcn_cvt_pk_f32_fp8(v0.y, false);
        a3 += __builtin_amdgcn_cvt_pk_f32_fp8(v0.y, true);
        b0 += __builtin_amdgcn_cvt_pk_f32_fp8(v1.x, false);
        b1 += __builtin_amdgcn_cvt_pk_f32_fp8(v1.x, true);
        b2 += __builtin_amdgcn_cvt_pk_f32_fp8(v1.y, false);
        b3 += __builtin_amdgcn_cvt_pk_f32_fp8(v1.y, true);
        a0 += __builtin_amdgcn_cvt_pk_f32_fp8(v2.x, false);
        a1 += __builtin_amdgcn_cvt_pk_f32_fp8(v2.x, true);
        a2 += __builtin_amdgcn_cvt_pk_f32_fp8(v2.y, false);
        a3 += __builtin_amdgcn_cvt_pk_f32_fp8(v2.y, true);
        b0 += __builtin_amdgcn_cvt_pk_f32_fp8(v3.x, false);
        b1 += __builtin_amdgcn_cvt_pk_f32_fp8(v3.x, true);
        b2 += __builtin_amdgcn_cvt_pk_f32_fp8(v3.y, false);
        b3 += __builtin_amdgcn_cvt_pk_f32_fp8(v3.y, true);
    }
    for (; i < end; ++i){
        int e = csr[i];
        uint2 v = x8[(size_t)e*16 + c];
        a0 += __builtin_amdgcn_cvt_pk_f32_fp8(v.x, false);
        a1 += __builtin_amdgcn_cvt_pk_f32_fp8(v.x, true);
        a2 += __builtin_amdgcn_cvt_pk_f32_fp8(v.y, false);
        a3 += __builtin_amdgcn_cvt_pk_f32_fp8(v.y, true);
    }
    a0 += b0; a1 += b1; a2 += b2; a3 += b3;
    float sc = 1.0f / (float)max(deg, 1);
    u4 o;
    o[0] = packh2(a0[0]*sc, a0[1]*sc);
    o[1] = packh2(a1[0]*sc, a1[1]*sc);
    o[2] = packh2(a2[0]*sc, a2[1]*sc);
    o[3] = packh2(a3[0]*sc, a3[1]*sc);
    *(u4*)(mh32 + (size_t)node*64 + 4*c) = o;
}

// ---------------- fused GEMM: layer-1 weights LDS-staged; H^T in-register; layer 2 fused; P,Q out fp8/fp16 ----------------
__global__ __launch_bounds__(256, 2) void k_gemm_fused(
    const _Float16* __restrict__ A0,   // m1h [M][128] f16
    const _Float16* __restrict__ A1,   // xh  [M][128] f16
    const h8* __restrict__ B0,         // wl1p frags (2048 h8)
    const h8* __restrict__ B1,         // wr1p frags (2048 h8)
    const float* __restrict__ bias1,
    const h8* __restrict__ W2l,        // wl2p frags
    const h8* __restrict__ W2r,        // wr2p frags
    const float* __restrict__ bias2,
    unsigned* __restrict__ P8,         // [M][16] u32 (64 fp8)
    uint2* __restrict__ Qh,            // [M][16] uint2 (64 f16)
    int M)
{
    __shared__ h8 shB[4096];           // 64 KB
    int tid = threadIdx.x;
    #pragma unroll
    for (int i = 0; i < 8; ++i) shB[i*256 + tid] = B0[i*256 + tid];
    #pragma unroll
    for (int i = 0; i < 8; ++i) shB[2048 + i*256 + tid] = B1[i*256 + tid];
    __syncthreads();

    int wid = tid >> 6, lane = tid & 63;
    int m0 = (blockIdx.x*4 + wid) * 16;
    if (m0 >= M) return;
    int m = lane & 15, kg = lane >> 4;
    int rowc = min(m0 + m, M-1);

    f4 acc[8];
    #pragma unroll
    for (int j = 0; j < 8; ++j) acc[j] = (f4)0.0f;

    #pragma unroll
    for (int ph = 0; ph < 2; ++ph){
        const _Float16* A = ph ? A1 : A0;
        #pragma unroll
        for (int kt = 0; kt < 4; ++kt){
            h8 nf = *(const h8*)(A + (size_t)rowc*128 + kt*32 + kg*8);
            #pragma unroll
            for (int j = 0; j < 8; ++j){
                h8 wf = shB[ph*2048 + (kt*8 + j)*64 + lane];
                acc[j] = __builtin_amdgcn_mfma_f32_16x16x32_f16(wf, nf, acc[j], 0, 0, 0);
            }
        }
    }

    unsigned hreg[16];
    #pragma unroll
    for (int j = 0; j < 8; ++j){
        f4 bb = *(const f4*)(bias1 + j*16 + kg*4);
        float v0 = acc[j][0] + bb[0]; v0 = v0 > 0.f ? v0 : 0.f;
        float v1 = acc[j][1] + bb[1]; v1 = v1 > 0.f ? v1 : 0.f;
        float v2 = acc[j][2] + bb[2]; v2 = v2 > 0.f ? v2 : 0.f;
        float v3 = acc[j][3] + bb[3]; v3 = v3 > 0.f ? v3 : 0.f;
        hreg[2*j]   = packh2(v0, v1);
        hreg[2*j+1] = packh2(v2, v3);
    }

    f4 accP[4], accQ[4];
    #pragma unroll
    for (int j = 0; j < 4; ++j){ accP[j] = (f4)0.0f; accQ[j] = (f4)0.0f; }

    int srcA = ((kg & 1) * 2) * 16 + m;
    int srcB = srcA + 16;
    bool hi = (kg >> 1) & 1;

    #pragma unroll
    for (int kt = 0; kt < 4; ++kt){
        unsigned sA0 = (unsigned)__shfl((int)hreg[4*kt+0], srcA, 64);
        unsigned sA1 = (unsigned)__shfl((int)hreg[4*kt+1], srcA, 64);
        unsigned sA2 = (unsigned)__shfl((int)hreg[4*kt+2], srcA, 64);
        unsigned sA3 = (unsigned)__shfl((int)hreg[4*kt+3], srcA, 64);
        unsigned sB0 = (unsigned)__shfl((int)hreg[4*kt+0], srcB, 64);
        unsigned sB1 = (unsigned)__shfl((int)hreg[4*kt+1], srcB, 64);
        unsigned sB2 = (unsigned)__shfl((int)hreg[4*kt+2], srcB, 64);
        unsigned sB3 = (unsigned)__shfl((int)hreg[4*kt+3], srcB, 64);
        u4 u;
        u[0] = hi ? sA2 : sA0;
        u[1] = hi ? sA3 : sA1;
        u[2] = hi ? sB2 : sB0;
        u[3] = hi ? sB3 : sB1;
        h8 hf = __builtin_bit_cast(h8, u);
        #pragma unroll
        for (int j2 = 0; j2 < 4; ++j2){
            accP[j2] = __builtin_amdgcn_mfma_f32_16x16x32_f16(W2l[(kt*4 + j2)*64 + lane], hf, accP[j2], 0, 0, 0);
            accQ[j2] = __builtin_amdgcn_mfma_f32_16x16x32_f16(W2r[(kt*4 + j2)*64 + lane], hf, accQ[j2], 0, 0, 0);
        }
    }

    int node = m0 + m;
    if (node < M){
        #pragma unroll
        for (int j2 = 0; j2 < 4; ++j2){
            int f = j2*16 + kg*4;
            int p8 = __builtin_amdgcn_cvt_pk_fp8_f32(accP[j2][0], accP[j2][1], 0, false);
            p8     = __builtin_amdgcn_cvt_pk_fp8_f32(accP[j2][2], accP[j2][3], p8, true);
            P8[(size_t)node*16 + j2*4 + kg] = (unsigned)p8;
            f4 bb2 = *(const f4*)(bias2 + f);
            uint2 qp;
            qp.x = packh2(accQ[j2][0] + bb2[0], accQ[j2][1] + bb2[1]);
            qp.y = packh2(accQ[j2][2] + bb2[2], accQ[j2][3] + bb2[3]);
            Qh[(size_t)node*16 + j2*4 + kg] = qp;
        }
    }
}

// ---------------- aggregation 2: out = Qh + mean-gather(P8); 16 lanes per node (lane c owns feats 4c..4c+3), unroll-4 ----------------
__global__ void k_agg2f(const int* __restrict__ row_start, const int* __restrict__ csr,
                        const unsigned* __restrict__ p8, const uint2* __restrict__ Qh,
                        float* __restrict__ out, int n){
    int node = (int)((blockIdx.x*(unsigned)blockDim.x + threadIdx.x) >> 4);
    int c = threadIdx.x & 15;
    if (node >= n) return;
    int base = row_start[node], end = row_start[node+1];
    int deg = end - base;
    f2 a0={0.f,0.f}, a1={0.f,0.f}, b0={0.f,0.f}, b1={0.f,0.f};
    f2 c0={0.f,0.f}, c1={0.f,0.f}, d0={0.f,0.f}, d1={0.f,0.f};
    int i = base;
    for (; i + 3 < end; i += 4){
        int e0 = csr[i], e1 = csr[i+1], e2 = csr[i+2], e3 = csr[i+3];
        unsigned v0 = p8[(size_t)e0*16 + c];
        unsigned v1 = p8[(size_t)e1*16 + c];
        unsigned v2 = p8[(size_t)e2*16 + c];
        unsigned v3 = p8[(size_t)e3*16 + c];
        a0 += __builtin_amdgcn_cvt_pk_f32_fp8(v0, false);
        a1 += __builtin_amdgcn_cvt_pk_f32_fp8(v0, true);
        b0 += __builtin_amdgcn_cvt_pk_f32_fp8(v1, false);
        b1 += __builtin_amdgcn_cvt_pk_f32_fp8(v1, true);
        c0 += __builtin_amdgcn_cvt_pk_f32_fp8(v2, false);
        c1 += __builtin_amdgcn_cvt_pk_f32_fp8(v2, true);
        d0 += __builtin_amdgcn_cvt_pk_f32_fp8(v3, false);
        d1 += __builtin_amdgcn_cvt_pk_f32_fp8(v3, true);
    }
    for (; i < end; ++i){
        int e = csr[i];
        unsigned v = p8[(size_t)e*16 + c];
        a0 += __builtin_amdgcn_cvt_pk_f32_fp8(v, false);
        a1 += __builtin_amdgcn_cvt_pk_f32_fp8(v, true);
    }
    a0 += b0 + c0 + d0;
    a1 += b1 + c1 + d1;
    float sc = 1.0f / (float)max(deg, 1);
    uint2 qh = Qh[(size_t)node*16 + c];
    f4 o;
    o[0] = a0[0]*sc + h2lo(qh.x);
    o[1] = a0[1]*sc + h2hi(qh.x);
    o[2] = a1[0]*sc + h2lo(qh.y);
    o[3] = a1[1]*sc + h2hi(qh.y);
    *(f4*)(out + (size_t)node*64 + 4*c) = o;
}

extern "C" void kernel_launch(void* const* d_in, const int* in_sizes, int n_in,
                              void* d_out, int out_size, void* d_ws, size_t ws_size,
                              hipStream_t stream) {
    const float* x   = (const float*)d_in[0];
    const int*   ei  = (const int*)d_in[1];
    const float* Wl1 = (const float*)d_in[2];
    const float* bl1 = (const float*)d_in[3];
    const float* Wr1 = (const float*)d_in[4];
    const float* Wl2 = (const float*)d_in[5];
    const float* bl2 = (const float*)d_in[6];
    const float* Wr2 = (const float*)d_in[7];

    const int N = in_sizes[0] / IN_C;
    const int E = in_sizes[1] / 2;
    const int* src = ei;
    const int* dst = ei + E;

    const int NBLK = (E + EPB - 1) / EPB;
    const int n_s  = NBUCK * NBLK;

    char* w = (char*)d_ws;
    size_t off = 0;
    auto alloc = [&](size_t bytes) -> char* {
        char* p = w + off;
        off = (off + bytes + 255) & ~(size_t)255;
        return p;
    };
    int* histT      = (int*)alloc((size_t)n_s*4);
    int* tmp        = (int*)alloc((size_t)n_s*4);
    int* bsum       = (int*)alloc(4096);
    unsigned* sorted= (unsigned*)alloc((size_t)E*4);
    int* csr        = (int*)alloc((size_t)E*4);
    int* row_start  = (int*)alloc((size_t)(N+1)*4);
    _Float16* xh    = (_Float16*)alloc((size_t)N*IN_C*2);
    unsigned* x8    = (unsigned*)alloc((size_t)N*IN_C);
    _Float16* m1h   = (_Float16*)alloc((size_t)N*IN_C*2);
    unsigned* p8    = (unsigned*)alloc((size_t)N*OUT_C);
    unsigned* qh    = (unsigned*)alloc((size_t)N*OUT_C*2);
    _Float16* wl1p  = (_Float16*)alloc(4*8*64*8*2);
    _Float16* wr1p  = (_Float16*)alloc(4*8*64*8*2);
    _Float16* wl2p  = (_Float16*)alloc(4*4*64*8*2);
    _Float16* wr2p  = (_Float16*)alloc(4*4*64*8*2);

    const int SB = (n_s + 255) / 256;
    const int n8 = N*IN_C/8;
    const int CVB = (n8 + 255)/256;

    k_front  <<<NBLK + 24 + CVB, 256, 0, stream>>>(dst, E, NBLK, histT,
                                                   x, (h8*)xh, (uint2*)x8, n8,
                                                   Wl1, Wr1, Wl2, Wr2, wl1p, wr1p, wl2p, wr2p);
    k_scanA  <<<SB, 256, 0, stream>>>(histT, tmp, bsum, n_s);
    k_scanB  <<<1, 256, 0, stream>>>(bsum, SB);
    k_scatter<<<NBLK, 256, 0, stream>>>(src, dst, E, tmp, bsum, NBLK, sorted);
    k_csr    <<<NBUCK, 512, 0, stream>>>(sorted, tmp, bsum, NBLK, E, N, csr, row_start);

    const int AB = (N + 15) / 16;    // 16 lanes per node, 16 nodes per block
    k_agg1<<<AB, 256, 0, stream>>>(row_start, csr, (const uint2*)x8, (unsigned*)m1h, N);

    const int GB2 = (N + 63)/64;
    k_gemm_fused<<<GB2, 256, 0, stream>>>(m1h, xh, (const h8*)wl1p, (const h8*)wr1p, bl1,
                                          (const h8*)wl2p, (const h8*)wr2p, bl2,
                                          p8, (uint2*)qh, N);

    k_agg2f<<<AB, 256, 0, stream>>>(row_start, csr, p8, (const uint2*)qh, (float*)d_out, N);
}

// Round 10
// 159.591 us; speedup vs baseline: 1.1815x; 1.0078x over previous
//
#include <hip/hip_runtime.h>
#include <hip/hip_bf16.h>
#include <stdint.h>

#define IN_C 128
#define HID_C 128
#define OUT_C 64

#define NBUCK 256
#define BSH 9
#define EPB 8192

typedef _Float16 h8 __attribute__((ext_vector_type(8)));
typedef _Float16 h2 __attribute__((ext_vector_type(2)));
typedef float f4 __attribute__((ext_vector_type(4)));
typedef float f2 __attribute__((ext_vector_type(2)));
typedef unsigned u4 __attribute__((ext_vector_type(4)));

__device__ inline float h2lo(unsigned v){ h2 t = __builtin_bit_cast(h2, v); return (float)t[0]; }
__device__ inline float h2hi(unsigned v){ h2 t = __builtin_bit_cast(h2, v); return (float)t[1]; }
__device__ inline unsigned packh2(float a, float b){ h2 t; t[0]=(_Float16)a; t[1]=(_Float16)b; return __builtin_bit_cast(unsigned, t); }

// ---------------- weight packing helper ----------------
__device__ inline void pack_one(const float* __restrict__ W, int C, _Float16* __restrict__ outp, int tid){
    int l = tid & 63;
    int f = tid >> 6;
    int NJT = C / 16;
    int kt = f / NJT;
    int jt = f - kt*NJT;
    int kbase = kt*32 + (l >> 4)*8;
    int col   = jt*16 + (l & 15);
    h8 o;
    #pragma unroll
    for (int r = 0; r < 8; ++r) o[r] = (_Float16)W[(kbase + r)*C + col];
    ((h8*)outp)[f*64 + l] = o;
}

// ---------------- front: hist (blocks [0,NBLK)) || pack || cvt (fp8 only) ----------------
__global__ __launch_bounds__(256) void k_front(const int* __restrict__ dst, int E, int NBLK,
                                               int* __restrict__ histT,
                                               const float* __restrict__ x,
                                               uint2* __restrict__ x8, int n8,
                                               const float* __restrict__ Wl1, const float* __restrict__ Wr1,
                                               const float* __restrict__ Wl2, const float* __restrict__ Wr2,
                                               _Float16* __restrict__ wl1p, _Float16* __restrict__ wr1p,
                                               _Float16* __restrict__ wl2p, _Float16* __restrict__ wr2p){
    __shared__ int h[NBUCK];
    int bid = blockIdx.x, t = threadIdx.x;
    if (bid < NBLK){
        h[t] = 0; __syncthreads();
        int e0 = bid*EPB, e1 = min(E, e0 + EPB);
        for (int e = e0 + t; e < e1; e += 256) atomicAdd(&h[((unsigned)dst[e]) >> BSH], 1);
        __syncthreads();
        histT[t*NBLK + bid] = h[t];
    } else if (bid < NBLK + 24){
        int tid = (bid - NBLK)*256 + t;
        if (tid < 2048)        pack_one(Wl1, 128, wl1p, tid);
        else if (tid < 4096)   pack_one(Wr1, 128, wr1p, tid - 2048);
        else if (tid < 5120)   pack_one(Wl2,  64, wl2p, tid - 4096);
        else if (tid < 6144)   pack_one(Wr2,  64, wr2p, tid - 5120);
    } else {
        int g = (bid - NBLK - 24)*256 + t;
        if (g < n8){
            const f4* xp = (const f4*)(x + (size_t)g*8);
            f4 a = xp[0], b = xp[1];
            int w0 = __builtin_amdgcn_cvt_pk_fp8_f32(a[0], a[1], 0, false);
            w0     = __builtin_amdgcn_cvt_pk_fp8_f32(a[2], a[3], w0, true);
            int w1 = __builtin_amdgcn_cvt_pk_fp8_f32(b[0], b[1], 0, false);
            w1     = __builtin_amdgcn_cvt_pk_fp8_f32(b[2], b[3], w1, true);
            uint2 p; p.x = (unsigned)w0; p.y = (unsigned)w1;
            x8[g] = p;
        }
    }
}

__global__ void k_scanA(const int* __restrict__ cnt, int* __restrict__ tmp, int* __restrict__ bsum, int n){
    __shared__ int s[256];
    int t = threadIdx.x, g = blockIdx.x*256 + t;
    int v = (g < n) ? cnt[g] : 0;
    s[t] = v; __syncthreads();
    for (int off = 1; off < 256; off <<= 1){
        int a = (t >= off) ? s[t-off] : 0;
        __syncthreads();
        s[t] += a;
        __syncthreads();
    }
    int excl = (t == 0) ? 0 : s[t-1];
    if (g < n) tmp[g] = excl;
    if (t == 255) bsum[blockIdx.x] = s[255];
}

__global__ void k_scanB(int* __restrict__ bsum, int nb){
    __shared__ int s[256];
    int t = threadIdx.x;
    int v = (t < nb) ? bsum[t] : 0;
    s[t] = v; __syncthreads();
    for (int off = 1; off < 256; off <<= 1){
        int a = (t >= off) ? s[t-off] : 0;
        __syncthreads();
        s[t] += a;
        __syncthreads();
    }
    int excl = (t == 0) ? 0 : s[t-1];
    if (t < nb) bsum[t] = excl;
}

// S[g] = tmp[g] + bsum[g>>8], computed on the fly
__global__ __launch_bounds__(256) void k_scatter(const int* __restrict__ src, const int* __restrict__ dst,
                                                 int E, const int* __restrict__ tmp, const int* __restrict__ bsum,
                                                 int NBLK, unsigned* __restrict__ sorted){
    __shared__ int off[NBUCK];
    int t = threadIdx.x;
    int g = t*NBLK + blockIdx.x;
    off[t] = tmp[g] + bsum[g >> 8];
    __syncthreads();
    int e0 = blockIdx.x*EPB, e1 = min(E, e0 + EPB);
    for (int e = e0 + t; e < e1; e += 256){
        int d = dst[e];
        int b = ((unsigned)d) >> BSH;
        int p = atomicAdd(&off[b], 1);
        sorted[p] = (unsigned)src[e] | (((unsigned)(d & ((1<<BSH)-1))) << 17);
    }
}

__global__ __launch_bounds__(512) void k_csr(const unsigned* __restrict__ sorted,
                                             const int* __restrict__ tmp, const int* __restrict__ bsum,
                                             int NBLK, int E, int N,
                                             int* __restrict__ csr, int* __restrict__ row_start){
    __shared__ int cnt[512];
    __shared__ int sc[512];
    int b = blockIdx.x, t = threadIdx.x;
    int i0 = b*NBLK;
    int bs = tmp[i0] + bsum[i0 >> 8];
    int be = (b == NBUCK-1) ? E : (tmp[i0 + NBLK] + bsum[(i0 + NBLK) >> 8]);
    cnt[t] = 0; __syncthreads();
    for (int e = bs + t; e < be; e += 512) atomicAdd(&cnt[sorted[e] >> 17], 1);
    __syncthreads();
    sc[t] = cnt[t]; __syncthreads();
    for (int off = 1; off < 512; off <<= 1){
        int a = (t >= off) ? sc[t-off] : 0;
        __syncthreads();
        sc[t] += a;
        __syncthreads();
    }
    int excl = sc[t] - cnt[t];
    int nid = (b << BSH) + t;
    if (nid < N) row_start[nid] = bs + excl;
    if (t == 0 && b == (N >> BSH)) row_start[N] = E;
    __syncthreads();
    cnt[t] = excl;
    __syncthreads();
    for (int e = bs + t; e < be; e += 512){
        unsigned v = sorted[e];
        int dl = v >> 17;
        int p = atomicAdd(&cnt[dl], 1);
        csr[bs + p] = (int)(v & 0x1FFFFu);
    }
}

// ---------------- aggregation 1: 16 lanes per node (lane c owns feats 8c..8c+7), unroll-8 ----------------
__global__ void k_agg1(const int* __restrict__ row_start, const int* __restrict__ csr,
                       const uint2* __restrict__ x8, unsigned* __restrict__ mh32, int n){
    int node = (int)((blockIdx.x*(unsigned)blockDim.x + threadIdx.x) >> 4);
    int c = threadIdx.x & 15;
    if (node >= n) return;
    int base = row_start[node], end = row_start[node+1];
    int deg = end - base;
    f2 a0={0.f,0.f}, a1={0.f,0.f}, a2={0.f,0.f}, a3={0.f,0.f};
    f2 b0={0.f,0.f}, b1={0.f,0.f}, b2={0.f,0.f}, b3={0.f,0.f};
    int i = base;
    for (; i + 7 < end; i += 8){
        int e0 = csr[i],   e1 = csr[i+1], e2 = csr[i+2], e3 = csr[i+3];
        int e4 = csr[i+4], e5 = csr[i+5], e6 = csr[i+6], e7 = csr[i+7];
        uint2 v0 = x8[(size_t)e0*16 + c];
        uint2 v1 = x8[(size_t)e1*16 + c];
        uint2 v2 = x8[(size_t)e2*16 + c];
        uint2 v3 = x8[(size_t)e3*16 + c];
        uint2 v4 = x8[(size_t)e4*16 + c];
        uint2 v5 = x8[(size_t)e5*16 + c];
        uint2 v6 = x8[(size_t)e6*16 + c];
        uint2 v7 = x8[(size_t)e7*16 + c];
        a0 += __builtin_amdgcn_cvt_pk_f32_fp8(v0.x, false);
        a1 += __builtin_amdgcn_cvt_pk_f32_fp8(v0.x, true);
        a2 += __builtin_amdgcn_cvt_pk_f32_fp8(v0.y, false);
        a3 += __builtin_amdgcn_cvt_pk_f32_fp8(v0.y, true);
        b0 += __builtin_amdgcn_cvt_pk_f32_fp8(v1.x, false);
        b1 += __builtin_amdgcn_cvt_pk_f32_fp8(v1.x, true);
        b2 += __builtin_amdgcn_cvt_pk_f32_fp8(v1.y, false);
        b3 += __builtin_amdgcn_cvt_pk_f32_fp8(v1.y, true);
        a0 += __builtin_amdgcn_cvt_pk_f32_fp8(v2.x, false);
        a1 += __builtin_amdgcn_cvt_pk_f32_fp8(v2.x, true);
        a2 += __builtin_amdgcn_cvt_pk_f32_fp8(v2.y, false);
        a3 += __builtin_amdgcn_cvt_pk_f32_fp8(v2.y, true);
        b0 += __builtin_amdgcn_cvt_pk_f32_fp8(v3.x, false);
        b1 += __builtin_amdgcn_cvt_pk_f32_fp8(v3.x, true);
        b2 += __builtin_amdgcn_cvt_pk_f32_fp8(v3.y, false);
        b3 += __builtin_amdgcn_cvt_pk_f32_fp8(v3.y, true);
        a0 += __builtin_amdgcn_cvt_pk_f32_fp8(v4.x, false);
        a1 += __builtin_amdgcn_cvt_pk_f32_fp8(v4.x, true);
        a2 += __builtin_amdgcn_cvt_pk_f32_fp8(v4.y, false);
        a3 += __builtin_amdgcn_cvt_pk_f32_fp8(v4.y, true);
        b0 += __builtin_amdgcn_cvt_pk_f32_fp8(v5.x, false);
        b1 += __builtin_amdgcn_cvt_pk_f32_fp8(v5.x, true);
        b2 += __builtin_amdgcn_cvt_pk_f32_fp8(v5.y, false);
        b3 += __builtin_amdgcn_cvt_pk_f32_fp8(v5.y, true);
        a0 += __builtin_amdgcn_cvt_pk_f32_fp8(v6.x, false);
        a1 += __builtin_amdgcn_cvt_pk_f32_fp8(v6.x, true);
        a2 += __builtin_amdgcn_cvt_pk_f32_fp8(v6.y, false);
        a3 += __builtin_amdgcn_cvt_pk_f32_fp8(v6.y, true);
        b0 += __builtin_amdgcn_cvt_pk_f32_fp8(v7.x, false);
        b1 += __builtin_amdgcn_cvt_pk_f32_fp8(v7.x, true);
        b2 += __builtin_amdgcn_cvt_pk_f32_fp8(v7.y, false);
        b3 += __builtin_amdgcn_cvt_pk_f32_fp8(v7.y, true);
    }
    for (; i + 3 < end; i += 4){
        int e0 = csr[i], e1 = csr[i+1], e2 = csr[i+2], e3 = csr[i+3];
        uint2 v0 = x8[(size_t)e0*16 + c];
        uint2 v1 = x8[(size_t)e1*16 + c];
        uint2 v2 = x8[(size_t)e2*16 + c];
        uint2 v3 = x8[(size_t)e3*16 + c];
        a0 += __builtin_amdgcn_cvt_pk_f32_fp8(v0.x, false);
        a1 += __builtin_amdgcn_cvt_pk_f32_fp8(v0.x, true);
        a2 += __builtin_amdgcn_cvt_pk_f32_fp8(v0.y, false);
        a3 += __builtin_amdgcn_cvt_pk_f32_fp8(v0.y, true);
        b0 += __builtin_amdgcn_cvt_pk_f32_fp8(v1.x, false);
        b1 += __builtin_amdgcn_cvt_pk_f32_fp8(v1.x, true);
        b2 += __builtin_amdgcn_cvt_pk_f32_fp8(v1.y, false);
        b3 += __builtin_amdgcn_cvt_pk_f32_fp8(v1.y, true);
        a0 += __builtin_amdgcn_cvt_pk_f32_fp8(v2.x, false);
        a1 += __builtin_amdgcn_cvt_pk_f32_fp8(v2.x, true);
        a2 += __builtin_amdgcn_cvt_pk_f32_fp8(v2.y, false);
        a3 += __builtin_amdgcn_cvt_pk_f32_fp8(v2.y, true);
        b0 += __builtin_amdgcn_cvt_pk_f32_fp8(v3.x, false);
        b1 += __builtin_amdgcn_cvt_pk_f32_fp8(v3.x, true);
        b2 += __builtin_amdgcn_cvt_pk_f32_fp8(v3.y, false);
        b3 += __builtin_amdgcn_cvt_pk_f32_fp8(v3.y, true);
    }
    for (; i < end; ++i){
        int e = csr[i];
        uint2 v = x8[(size_t)e*16 + c];
        a0 += __builtin_amdgcn_cvt_pk_f32_fp8(v.x, false);
        a1 += __builtin_amdgcn_cvt_pk_f32_fp8(v.x, true);
        a2 += __builtin_amdgcn_cvt_pk_f32_fp8(v.y, false);
        a3 += __builtin_amdgcn_cvt_pk_f32_fp8(v.y, true);
    }
    a0 += b0; a1 += b1; a2 += b2; a3 += b3;
    float sc = 1.0f / (float)max(deg, 1);
    u4 o;
    o[0] = packh2(a0[0]*sc, a0[1]*sc);
    o[1] = packh2(a1[0]*sc, a1[1]*sc);
    o[2] = packh2(a2[0]*sc, a2[1]*sc);
    o[3] = packh2(a3[0]*sc, a3[1]*sc);
    *(u4*)(mh32 + (size_t)node*64 + 4*c) = o;
}

// ---------------- fused GEMM: layer-1 weights LDS-staged; self term from x fp32; layer 2 fused ----------------
__global__ __launch_bounds__(256, 2) void k_gemm_fused(
    const _Float16* __restrict__ A0,   // m1h [M][128] f16
    const float* __restrict__ X,       // x   [M][128] f32
    const h8* __restrict__ B0,         // wl1p frags (2048 h8)
    const h8* __restrict__ B1,         // wr1p frags (2048 h8)
    const float* __restrict__ bias1,
    const h8* __restrict__ W2l,        // wl2p frags
    const h8* __restrict__ W2r,        // wr2p frags
    const float* __restrict__ bias2,
    unsigned* __restrict__ P8,         // [M][16] u32 (64 fp8)
    uint2* __restrict__ Qh,            // [M][16] uint2 (64 f16)
    int M)
{
    __shared__ h8 shB[4096];           // 64 KB
    int tid = threadIdx.x;
    #pragma unroll
    for (int i = 0; i < 8; ++i) shB[i*256 + tid] = B0[i*256 + tid];
    #pragma unroll
    for (int i = 0; i < 8; ++i) shB[2048 + i*256 + tid] = B1[i*256 + tid];
    __syncthreads();

    int wid = tid >> 6, lane = tid & 63;
    int m0 = (blockIdx.x*4 + wid) * 16;
    if (m0 >= M) return;
    int m = lane & 15, kg = lane >> 4;
    int rowc = min(m0 + m, M-1);

    f4 acc[8];
    #pragma unroll
    for (int j = 0; j < 8; ++j) acc[j] = (f4)0.0f;

    // phase 0: neighbor-mean term (f16 rows)
    #pragma unroll
    for (int kt = 0; kt < 4; ++kt){
        h8 nf = *(const h8*)(A0 + (size_t)rowc*128 + kt*32 + kg*8);
        #pragma unroll
        for (int j = 0; j < 8; ++j){
            h8 wf = shB[(kt*8 + j)*64 + lane];
            acc[j] = __builtin_amdgcn_mfma_f32_16x16x32_f16(wf, nf, acc[j], 0, 0, 0);
        }
    }
    // phase 1: self term (f32 rows, convert in-register)
    #pragma unroll
    for (int kt = 0; kt < 4; ++kt){
        const float* xr = X + (size_t)rowc*128 + kt*32 + kg*8;
        f4 xa = *(const f4*)(xr);
        f4 xb = *(const f4*)(xr + 4);
        h8 nf;
        nf[0]=(_Float16)xa[0]; nf[1]=(_Float16)xa[1]; nf[2]=(_Float16)xa[2]; nf[3]=(_Float16)xa[3];
        nf[4]=(_Float16)xb[0]; nf[5]=(_Float16)xb[1]; nf[6]=(_Float16)xb[2]; nf[7]=(_Float16)xb[3];
        #pragma unroll
        for (int j = 0; j < 8; ++j){
            h8 wf = shB[2048 + (kt*8 + j)*64 + lane];
            acc[j] = __builtin_amdgcn_mfma_f32_16x16x32_f16(wf, nf, acc[j], 0, 0, 0);
        }
    }

    unsigned hreg[16];
    #pragma unroll
    for (int j = 0; j < 8; ++j){
        f4 bb = *(const f4*)(bias1 + j*16 + kg*4);
        float v0 = acc[j][0] + bb[0]; v0 = v0 > 0.f ? v0 : 0.f;
        float v1 = acc[j][1] + bb[1]; v1 = v1 > 0.f ? v1 : 0.f;
        float v2 = acc[j][2] + bb[2]; v2 = v2 > 0.f ? v2 : 0.f;
        float v3 = acc[j][3] + bb[3]; v3 = v3 > 0.f ? v3 : 0.f;
        hreg[2*j]   = packh2(v0, v1);
        hreg[2*j+1] = packh2(v2, v3);
    }

    f4 accP[4], accQ[4];
    #pragma unroll
    for (int j = 0; j < 4; ++j){ accP[j] = (f4)0.0f; accQ[j] = (f4)0.0f; }

    int srcA = ((kg & 1) * 2) * 16 + m;
    int srcB = srcA + 16;
    bool hi = (kg >> 1) & 1;

    #pragma unroll
    for (int kt = 0; kt < 4; ++kt){
        unsigned sA0 = (unsigned)__shfl((int)hreg[4*kt+0], srcA, 64);
        unsigned sA1 = (unsigned)__shfl((int)hreg[4*kt+1], srcA, 64);
        unsigned sA2 = (unsigned)__shfl((int)hreg[4*kt+2], srcA, 64);
        unsigned sA3 = (unsigned)__shfl((int)hreg[4*kt+3], srcA, 64);
        unsigned sB0 = (unsigned)__shfl((int)hreg[4*kt+0], srcB, 64);
        unsigned sB1 = (unsigned)__shfl((int)hreg[4*kt+1], srcB, 64);
        unsigned sB2 = (unsigned)__shfl((int)hreg[4*kt+2], srcB, 64);
        unsigned sB3 = (unsigned)__shfl((int)hreg[4*kt+3], srcB, 64);
        u4 u;
        u[0] = hi ? sA2 : sA0;
        u[1] = hi ? sA3 : sA1;
        u[2] = hi ? sB2 : sB0;
        u[3] = hi ? sB3 : sB1;
        h8 hf = __builtin_bit_cast(h8, u);
        #pragma unroll
        for (int j2 = 0; j2 < 4; ++j2){
            accP[j2] = __builtin_amdgcn_mfma_f32_16x16x32_f16(W2l[(kt*4 + j2)*64 + lane], hf, accP[j2], 0, 0, 0);
            accQ[j2] = __builtin_amdgcn_mfma_f32_16x16x32_f16(W2r[(kt*4 + j2)*64 + lane], hf, accQ[j2], 0, 0, 0);
        }
    }

    int node = m0 + m;
    if (node < M){
        #pragma unroll
        for (int j2 = 0; j2 < 4; ++j2){
            int f = j2*16 + kg*4;
            int p8 = __builtin_amdgcn_cvt_pk_fp8_f32(accP[j2][0], accP[j2][1], 0, false);
            p8     = __builtin_amdgcn_cvt_pk_fp8_f32(accP[j2][2], accP[j2][3], p8, true);
            P8[(size_t)node*16 + j2*4 + kg] = (unsigned)p8;
            f4 bb2 = *(const f4*)(bias2 + f);
            uint2 qp;
            qp.x = packh2(accQ[j2][0] + bb2[0], accQ[j2][1] + bb2[1]);
            qp.y = packh2(accQ[j2][2] + bb2[2], accQ[j2][3] + bb2[3]);
            Qh[(size_t)node*16 + j2*4 + kg] = qp;
        }
    }
}

// ---------------- aggregation 2: out = Qh + mean-gather(P8); 16 lanes per node, unroll-8 ----------------
__global__ void k_agg2f(const int* __restrict__ row_start, const int* __restrict__ csr,
                        const unsigned* __restrict__ p8, const uint2* __restrict__ Qh,
                        float* __restrict__ out, int n){
    int node = (int)((blockIdx.x*(unsigned)blockDim.x + threadIdx.x) >> 4);
    int c = threadIdx.x & 15;
    if (node >= n) return;
    int base = row_start[node], end = row_start[node+1];
    int deg = end - base;
    f2 a0={0.f,0.f}, a1={0.f,0.f}, b0={0.f,0.f}, b1={0.f,0.f};
    f2 c0={0.f,0.f}, c1={0.f,0.f}, d0={0.f,0.f}, d1={0.f,0.f};
    int i = base;
    for (; i + 7 < end; i += 8){
        int e0 = csr[i],   e1 = csr[i+1], e2 = csr[i+2], e3 = csr[i+3];
        int e4 = csr[i+4], e5 = csr[i+5], e6 = csr[i+6], e7 = csr[i+7];
        unsigned v0 = p8[(size_t)e0*16 + c];
        unsigned v1 = p8[(size_t)e1*16 + c];
        unsigned v2 = p8[(size_t)e2*16 + c];
        unsigned v3 = p8[(size_t)e3*16 + c];
        unsigned v4 = p8[(size_t)e4*16 + c];
        unsigned v5 = p8[(size_t)e5*16 + c];
        unsigned v6 = p8[(size_t)e6*16 + c];
        unsigned v7 = p8[(size_t)e7*16 + c];
        a0 += __builtin_amdgcn_cvt_pk_f32_fp8(v0, false);
        a1 += __builtin_amdgcn_cvt_pk_f32_fp8(v0, true);
        b0 += __builtin_amdgcn_cvt_pk_f32_fp8(v1, false);
        b1 += __builtin_amdgcn_cvt_pk_f32_fp8(v1, true);
        c0 += __builtin_amdgcn_cvt_pk_f32_fp8(v2, false);
        c1 += __builtin_amdgcn_cvt_pk_f32_fp8(v2, true);
        d0 += __builtin_amdgcn_cvt_pk_f32_fp8(v3, false);
        d1 += __builtin_amdgcn_cvt_pk_f32_fp8(v3, true);
        a0 += __builtin_amdgcn_cvt_pk_f32_fp8(v4, false);
        a1 += __builtin_amdgcn_cvt_pk_f32_fp8(v4, true);
        b0 += __builtin_amdgcn_cvt_pk_f32_fp8(v5, false);
        b1 += __builtin_amdgcn_cvt_pk_f32_fp8(v5, true);
        c0 += __builtin_amdgcn_cvt_pk_f32_fp8(v6, false);
        c1 += __builtin_amdgcn_cvt_pk_f32_fp8(v6, true);
        d0 += __builtin_amdgcn_cvt_pk_f32_fp8(v7, false);
        d1 += __builtin_amdgcn_cvt_pk_f32_fp8(v7, true);
    }
    for (; i + 3 < end; i += 4){
        int e0 = csr[i], e1 = csr[i+1], e2 = csr[i+2], e3 = csr[i+3];
        unsigned v0 = p8[(size_t)e0*16 + c];
        unsigned v1 = p8[(size_t)e1*16 + c];
        unsigned v2 = p8[(size_t)e2*16 + c];
        unsigned v3 = p8[(size_t)e3*16 + c];
        a0 += __builtin_amdgcn_cvt_pk_f32_fp8(v0, false);
        a1 += __builtin_amdgcn_cvt_pk_f32_fp8(v0, true);
        b0 += __builtin_amdgcn_cvt_pk_f32_fp8(v1, false);
        b1 += __builtin_amdgcn_cvt_pk_f32_fp8(v1, true);
        c0 += __builtin_amdgcn_cvt_pk_f32_fp8(v2, false);
        c1 += __builtin_amdgcn_cvt_pk_f32_fp8(v2, true);
        d0 += __builtin_amdgcn_cvt_pk_f32_fp8(v3, false);
        d1 += __builtin_amdgcn_cvt_pk_f32_fp8(v3, true);
    }
    for (; i < end; ++i){
        int e = csr[i];
        unsigned v = p8[(size_t)e*16 + c];
        a0 += __builtin_amdgcn_cvt_pk_f32_fp8(v, false);
        a1 += __builtin_amdgcn_cvt_pk_f32_fp8(v, true);
    }
    a0 += b0 + c0 + d0;
    a1 += b1 + c1 + d1;
    float sc = 1.0f / (float)max(deg, 1);
    uint2 qh = Qh[(size_t)node*16 + c];
    f4 o;
    o[0] = a0[0]*sc + h2lo(qh.x);
    o[1] = a0[1]*sc + h2hi(qh.x);
    o[2] = a1[0]*sc + h2lo(qh.y);
    o[3] = a1[1]*sc + h2hi(qh.y);
    *(f4*)(out + (size_t)node*64 + 4*c) = o;
}

extern "C" void kernel_launch(void* const* d_in, const int* in_sizes, int n_in,
                              void* d_out, int out_size, void* d_ws, size_t ws_size,
                              hipStream_t stream) {
    const float* x   = (const float*)d_in[0];
    const int*   ei  = (const int*)d_in[1];
    const float* Wl1 = (const float*)d_in[2];
    const float* bl1 = (const float*)d_in[3];
    const float* Wr1 = (const float*)d_in[4];
    const float* Wl2 = (const float*)d_in[5];
    const float* bl2 = (const float*)d_in[6];
    const float* Wr2 = (const float*)d_in[7];

    const int N = in_sizes[0] / IN_C;
    const int E = in_sizes[1] / 2;
    const int* src = ei;
    const int* dst = ei + E;

    const int NBLK = (E + EPB - 1) / EPB;
    const int n_s  = NBUCK * NBLK;

    char* w = (char*)d_ws;
    size_t off = 0;
    auto alloc = [&](size_t bytes) -> char* {
        char* p = w + off;
        off = (off + bytes + 255) & ~(size_t)255;
        return p;
    };
    int* histT      = (int*)alloc((size_t)n_s*4);
    int* tmp        = (int*)alloc((size_t)n_s*4);
    int* bsum       = (int*)alloc(4096);
    unsigned* sorted= (unsigned*)alloc((size_t)E*4);
    int* csr        = (int*)alloc((size_t)E*4);
    int* row_start  = (int*)alloc((size_t)(N+1)*4);
    unsigned* x8    = (unsigned*)alloc((size_t)N*IN_C);
    _Float16* m1h   = (_Float16*)alloc((size_t)N*IN_C*2);
    unsigned* p8    = (unsigned*)alloc((size_t)N*OUT_C);
    unsigned* qh    = (unsigned*)alloc((size_t)N*OUT_C*2);
    _Float16* wl1p  = (_Float16*)alloc(4*8*64*8*2);
    _Float16* wr1p  = (_Float16*)alloc(4*8*64*8*2);
    _Float16* wl2p  = (_Float16*)alloc(4*4*64*8*2);
    _Float16* wr2p  = (_Float16*)alloc(4*4*64*8*2);

    const int SB = (n_s + 255) / 256;
    const int n8 = N*IN_C/8;
    const int CVB = (n8 + 255)/256;

    k_front  <<<NBLK + 24 + CVB, 256, 0, stream>>>(dst, E, NBLK, histT,
                                                   x, (uint2*)x8, n8,
                                                   Wl1, Wr1, Wl2, Wr2, wl1p, wr1p, wl2p, wr2p);
    k_scanA  <<<SB, 256, 0, stream>>>(histT, tmp, bsum, n_s);
    k_scanB  <<<1, 256, 0, stream>>>(bsum, SB);
    k_scatter<<<NBLK, 256, 0, stream>>>(src, dst, E, tmp, bsum, NBLK, sorted);
    k_csr    <<<NBUCK, 512, 0, stream>>>(sorted, tmp, bsum, NBLK, E, N, csr, row_start);

    const int AB = (N + 15) / 16;    // 16 lanes per node, 16 nodes per block
    k_agg1<<<AB, 256, 0, stream>>>(row_start, csr, (const uint2*)x8, (unsigned*)m1h, N);

    const int GB2 = (N + 63)/64;
    k_gemm_fused<<<GB2, 256, 0, stream>>>(m1h, x, (const h8*)wl1p, (const h8*)wr1p, bl1,
                                          (const h8*)wl2p, (const h8*)wr2p, bl2,
                                          p8, (uint2*)qh, N);

    k_agg2f<<<AB, 256, 0, stream>>>(row_start, csr, p8, (const uint2*)qh, (float*)d_out, N);
}

// Round 11
// 148.118 us; speedup vs baseline: 1.2730x; 1.0775x over previous
//
#include <hip/hip_runtime.h>
#include <hip/hip_bf16.h>
#include <stdint.h>

#define IN_C 128
#define HID_C 128
#define OUT_C 64

#define NBUCK 256
#define BSH 9
#define EPB 2048

typedef _Float16 h8 __attribute__((ext_vector_type(8)));
typedef _Float16 h2 __attribute__((ext_vector_type(2)));
typedef float f4 __attribute__((ext_vector_type(4)));
typedef float f2 __attribute__((ext_vector_type(2)));
typedef unsigned u4 __attribute__((ext_vector_type(4)));

__device__ inline float h2lo(unsigned v){ h2 t = __builtin_bit_cast(h2, v); return (float)t[0]; }
__device__ inline float h2hi(unsigned v){ h2 t = __builtin_bit_cast(h2, v); return (float)t[1]; }
__device__ inline unsigned packh2(float a, float b){ h2 t; t[0]=(_Float16)a; t[1]=(_Float16)b; return __builtin_bit_cast(unsigned, t); }

// ---------------- weight packing helper ----------------
__device__ inline void pack_one(const float* __restrict__ W, int C, _Float16* __restrict__ outp, int tid){
    int l = tid & 63;
    int f = tid >> 6;
    int NJT = C / 16;
    int kt = f / NJT;
    int jt = f - kt*NJT;
    int kbase = kt*32 + (l >> 4)*8;
    int col   = jt*16 + (l & 15);
    h8 o;
    #pragma unroll
    for (int r = 0; r < 8; ++r) o[r] = (_Float16)W[(kbase + r)*C + col];
    ((h8*)outp)[f*64 + l] = o;
}

// ---------------- front: hist (blocks [0,NBLK)) || pack || cvt (fp8 only) ----------------
__global__ __launch_bounds__(256) void k_front(const int* __restrict__ dst, int E, int NBLK,
                                               int* __restrict__ histT,
                                               const float* __restrict__ x,
                                               uint2* __restrict__ x8, int n8,
                                               const float* __restrict__ Wl1, const float* __restrict__ Wr1,
                                               const float* __restrict__ Wl2, const float* __restrict__ Wr2,
                                               _Float16* __restrict__ wl1p, _Float16* __restrict__ wr1p,
                                               _Float16* __restrict__ wl2p, _Float16* __restrict__ wr2p){
    __shared__ int h[NBUCK];
    int bid = blockIdx.x, t = threadIdx.x;
    if (bid < NBLK){
        h[t] = 0; __syncthreads();
        int e0 = bid*EPB, e1 = min(E, e0 + EPB);
        for (int e = e0 + t; e < e1; e += 256) atomicAdd(&h[((unsigned)dst[e]) >> BSH], 1);
        __syncthreads();
        histT[t*NBLK + bid] = h[t];
    } else if (bid < NBLK + 24){
        int tid = (bid - NBLK)*256 + t;
        if (tid < 2048)        pack_one(Wl1, 128, wl1p, tid);
        else if (tid < 4096)   pack_one(Wr1, 128, wr1p, tid - 2048);
        else if (tid < 5120)   pack_one(Wl2,  64, wl2p, tid - 4096);
        else if (tid < 6144)   pack_one(Wr2,  64, wr2p, tid - 5120);
    } else {
        int g = (bid - NBLK - 24)*256 + t;
        if (g < n8){
            const f4* xp = (const f4*)(x + (size_t)g*8);
            f4 a = xp[0], b = xp[1];
            int w0 = __builtin_amdgcn_cvt_pk_fp8_f32(a[0], a[1], 0, false);
            w0     = __builtin_amdgcn_cvt_pk_fp8_f32(a[2], a[3], w0, true);
            int w1 = __builtin_amdgcn_cvt_pk_fp8_f32(b[0], b[1], 0, false);
            w1     = __builtin_amdgcn_cvt_pk_fp8_f32(b[2], b[3], w1, true);
            uint2 p; p.x = (unsigned)w0; p.y = (unsigned)w1;
            x8[g] = p;
        }
    }
}

__global__ void k_scanA(const int* __restrict__ cnt, int* __restrict__ tmp, int* __restrict__ bsum, int n){
    __shared__ int s[256];
    int t = threadIdx.x, g = blockIdx.x*256 + t;
    int v = (g < n) ? cnt[g] : 0;
    s[t] = v; __syncthreads();
    for (int off = 1; off < 256; off <<= 1){
        int a = (t >= off) ? s[t-off] : 0;
        __syncthreads();
        s[t] += a;
        __syncthreads();
    }
    int excl = (t == 0) ? 0 : s[t-1];
    if (g < n) tmp[g] = excl;
    if (t == 255) bsum[blockIdx.x] = s[255];
}

__global__ void k_scanB(int* __restrict__ bsum, int nb){
    __shared__ int s[1024];
    int t = threadIdx.x;
    int v = (t < nb) ? bsum[t] : 0;
    s[t] = v; __syncthreads();
    for (int off = 1; off < 1024; off <<= 1){
        int a = (t >= off) ? s[t-off] : 0;
        __syncthreads();
        s[t] += a;
        __syncthreads();
    }
    int excl = (t == 0) ? 0 : s[t-1];
    if (t < nb) bsum[t] = excl;
}

// S[g] = tmp[g] + bsum[g>>8], computed on the fly
__global__ __launch_bounds__(256) void k_scatter(const int* __restrict__ src, const int* __restrict__ dst,
                                                 int E, const int* __restrict__ tmp, const int* __restrict__ bsum,
                                                 int NBLK, unsigned* __restrict__ sorted){
    __shared__ int off[NBUCK];
    int t = threadIdx.x;
    int g = t*NBLK + blockIdx.x;
    off[t] = tmp[g] + bsum[g >> 8];
    __syncthreads();
    int e0 = blockIdx.x*EPB, e1 = min(E, e0 + EPB);
    for (int e = e0 + t; e < e1; e += 256){
        int d = dst[e];
        int b = ((unsigned)d) >> BSH;
        int p = atomicAdd(&off[b], 1);
        sorted[p] = (unsigned)src[e] | (((unsigned)(d & ((1<<BSH)-1))) << 17);
    }
}

__global__ __launch_bounds__(512) void k_csr(const unsigned* __restrict__ sorted,
                                             const int* __restrict__ tmp, const int* __restrict__ bsum,
                                             int NBLK, int E, int N,
                                             int* __restrict__ csr, int* __restrict__ row_start){
    __shared__ int cnt[512];
    __shared__ int sc[512];
    int b = blockIdx.x, t = threadIdx.x;
    int i0 = b*NBLK;
    int bs = tmp[i0] + bsum[i0 >> 8];
    int be = (b == NBUCK-1) ? E : (tmp[i0 + NBLK] + bsum[(i0 + NBLK) >> 8]);
    cnt[t] = 0; __syncthreads();
    for (int e = bs + t; e < be; e += 512) atomicAdd(&cnt[sorted[e] >> 17], 1);
    __syncthreads();
    sc[t] = cnt[t]; __syncthreads();
    for (int off = 1; off < 512; off <<= 1){
        int a = (t >= off) ? sc[t-off] : 0;
        __syncthreads();
        sc[t] += a;
        __syncthreads();
    }
    int excl = sc[t] - cnt[t];
    int nid = (b << BSH) + t;
    if (nid < N) row_start[nid] = bs + excl;
    if (t == 0 && b == (N >> BSH)) row_start[N] = E;
    __syncthreads();
    cnt[t] = excl;
    __syncthreads();
    for (int e = bs + t; e < be; e += 512){
        unsigned v = sorted[e];
        int dl = v >> 17;
        int p = atomicAdd(&cnt[dl], 1);
        csr[bs + p] = (int)(v & 0x1FFFFu);
    }
}

// ---------------- aggregation 1: 16 lanes per node (lane c owns feats 8c..8c+7), unroll-8 ----------------
__global__ void k_agg1(const int* __restrict__ row_start, const int* __restrict__ csr,
                       const uint2* __restrict__ x8, unsigned* __restrict__ mh32, int n){
    int node = (int)((blockIdx.x*(unsigned)blockDim.x + threadIdx.x) >> 4);
    int c = threadIdx.x & 15;
    if (node >= n) return;
    int base = row_start[node], end = row_start[node+1];
    int deg = end - base;
    f2 a0={0.f,0.f}, a1={0.f,0.f}, a2={0.f,0.f}, a3={0.f,0.f};
    f2 b0={0.f,0.f}, b1={0.f,0.f}, b2={0.f,0.f}, b3={0.f,0.f};
    int i = base;
    for (; i + 7 < end; i += 8){
        int e0 = csr[i],   e1 = csr[i+1], e2 = csr[i+2], e3 = csr[i+3];
        int e4 = csr[i+4], e5 = csr[i+5], e6 = csr[i+6], e7 = csr[i+7];
        uint2 v0 = x8[(size_t)e0*16 + c];
        uint2 v1 = x8[(size_t)e1*16 + c];
        uint2 v2 = x8[(size_t)e2*16 + c];
        uint2 v3 = x8[(size_t)e3*16 + c];
        uint2 v4 = x8[(size_t)e4*16 + c];
        uint2 v5 = x8[(size_t)e5*16 + c];
        uint2 v6 = x8[(size_t)e6*16 + c];
        uint2 v7 = x8[(size_t)e7*16 + c];
        a0 += __builtin_amdgcn_cvt_pk_f32_fp8(v0.x, false);
        a1 += __builtin_amdgcn_cvt_pk_f32_fp8(v0.x, true);
        a2 += __builtin_amdgcn_cvt_pk_f32_fp8(v0.y, false);
        a3 += __builtin_amdgcn_cvt_pk_f32_fp8(v0.y, true);
        b0 += __builtin_amdgcn_cvt_pk_f32_fp8(v1.x, false);
        b1 += __builtin_amdgcn_cvt_pk_f32_fp8(v1.x, true);
        b2 += __builtin_amdgcn_cvt_pk_f32_fp8(v1.y, false);
        b3 += __builtin_amdgcn_cvt_pk_f32_fp8(v1.y, true);
        a0 += __builtin_amdgcn_cvt_pk_f32_fp8(v2.x, false);
        a1 += __builtin_amdgcn_cvt_pk_f32_fp8(v2.x, true);
        a2 += __builtin_amdgcn_cvt_pk_f32_fp8(v2.y, false);
        a3 += __builtin_amdgcn_cvt_pk_f32_fp8(v2.y, true);
        b0 += __builtin_amdgcn_cvt_pk_f32_fp8(v3.x, false);
        b1 += __builtin_amdgcn_cvt_pk_f32_fp8(v3.x, true);
        b2 += __builtin_amdgcn_cvt_pk_f32_fp8(v3.y, false);
        b3 += __builtin_amdgcn_cvt_pk_f32_fp8(v3.y, true);
        a0 += __builtin_amdgcn_cvt_pk_f32_fp8(v4.x, false);
        a1 += __builtin_amdgcn_cvt_pk_f32_fp8(v4.x, true);
        a2 += __builtin_amdgcn_cvt_pk_f32_fp8(v4.y, false);
        a3 += __builtin_amdgcn_cvt_pk_f32_fp8(v4.y, true);
        b0 += __builtin_amdgcn_cvt_pk_f32_fp8(v5.x, false);
        b1 += __builtin_amdgcn_cvt_pk_f32_fp8(v5.x, true);
        b2 += __builtin_amdgcn_cvt_pk_f32_fp8(v5.y, false);
        b3 += __builtin_amdgcn_cvt_pk_f32_fp8(v5.y, true);
        a0 += __builtin_amdgcn_cvt_pk_f32_fp8(v6.x, false);
        a1 += __builtin_amdgcn_cvt_pk_f32_fp8(v6.x, true);
        a2 += __builtin_amdgcn_cvt_pk_f32_fp8(v6.y, false);
        a3 += __builtin_amdgcn_cvt_pk_f32_fp8(v6.y, true);
        b0 += __builtin_amdgcn_cvt_pk_f32_fp8(v7.x, false);
        b1 += __builtin_amdgcn_cvt_pk_f32_fp8(v7.x, true);
        b2 += __builtin_amdgcn_cvt_pk_f32_fp8(v7.y, false);
        b3 += __builtin_amdgcn_cvt_pk_f32_fp8(v7.y, true);
    }
    for (; i + 3 < end; i += 4){
        int e0 = csr[i], e1 = csr[i+1], e2 = csr[i+2], e3 = csr[i+3];
        uint2 v0 = x8[(size_t)e0*16 + c];
        uint2 v1 = x8[(size_t)e1*16 + c];
        uint2 v2 = x8[(size_t)e2*16 + c];
        uint2 v3 = x8[(size_t)e3*16 + c];
        a0 += __builtin_amdgcn_cvt_pk_f32_fp8(v0.x, false);
        a1 += __builtin_amdgcn_cvt_pk_f32_fp8(v0.x, true);
        a2 += __builtin_amdgcn_cvt_pk_f32_fp8(v0.y, false);
        a3 += __builtin_amdgcn_cvt_pk_f32_fp8(v0.y, true);
        b0 += __builtin_amdgcn_cvt_pk_f32_fp8(v1.x, false);
        b1 += __builtin_amdgcn_cvt_pk_f32_fp8(v1.x, true);
        b2 += __builtin_amdgcn_cvt_pk_f32_fp8(v1.y, false);
        b3 += __builtin_amdgcn_cvt_pk_f32_fp8(v1.y, true);
        a0 += __builtin_amdgcn_cvt_pk_f32_fp8(v2.x, false);
        a1 += __builtin_amdgcn_cvt_pk_f32_fp8(v2.x, true);
        a2 += __builtin_amdgcn_cvt_pk_f32_fp8(v2.y, false);
        a3 += __builtin_amdgcn_cvt_pk_f32_fp8(v2.y, true);
        b0 += __builtin_amdgcn_cvt_pk_f32_fp8(v3.x, false);
        b1 += __builtin_amdgcn_cvt_pk_f32_fp8(v3.x, true);
        b2 += __builtin_amdgcn_cvt_pk_f32_fp8(v3.y, false);
        b3 += __builtin_amdgcn_cvt_pk_f32_fp8(v3.y, true);
    }
    for (; i < end; ++i){
        int e = csr[i];
        uint2 v = x8[(size_t)e*16 + c];
        a0 += __builtin_amdgcn_cvt_pk_f32_fp8(v.x, false);
        a1 += __builtin_amdgcn_cvt_pk_f32_fp8(v.x, true);
        a2 += __builtin_amdgcn_cvt_pk_f32_fp8(v.y, false);
        a3 += __builtin_amdgcn_cvt_pk_f32_fp8(v.y, true);
    }
    a0 += b0; a1 += b1; a2 += b2; a3 += b3;
    float sc = 1.0f / (float)max(deg, 1);
    u4 o;
    o[0] = packh2(a0[0]*sc, a0[1]*sc);
    o[1] = packh2(a1[0]*sc, a1[1]*sc);
    o[2] = packh2(a2[0]*sc, a2[1]*sc);
    o[3] = packh2(a3[0]*sc, a3[1]*sc);
    *(u4*)(mh32 + (size_t)node*64 + 4*c) = o;
}

// ---------------- fused GEMM: 512-thread blocks (8 waves), layer-1 weights LDS-staged ----------------
__global__ __launch_bounds__(512, 4) void k_gemm_fused(
    const _Float16* __restrict__ A0,   // m1h [M][128] f16
    const float* __restrict__ X,       // x   [M][128] f32
    const h8* __restrict__ B0,         // wl1p frags (2048 h8)
    const h8* __restrict__ B1,         // wr1p frags (2048 h8)
    const float* __restrict__ bias1,
    const h8* __restrict__ W2l,        // wl2p frags
    const h8* __restrict__ W2r,        // wr2p frags
    const float* __restrict__ bias2,
    unsigned* __restrict__ P8,         // [M][16] u32 (64 fp8)
    uint2* __restrict__ Qh,            // [M][16] uint2 (64 f16)
    int M)
{
    __shared__ h8 shB[4096];           // 64 KB
    int tid = threadIdx.x;
    #pragma unroll
    for (int i = 0; i < 4; ++i) shB[i*512 + tid] = B0[i*512 + tid];
    #pragma unroll
    for (int i = 0; i < 4; ++i) shB[2048 + i*512 + tid] = B1[i*512 + tid];
    __syncthreads();

    int wid = tid >> 6, lane = tid & 63;
    int m0 = (blockIdx.x*8 + wid) * 16;
    if (m0 >= M) return;
    int m = lane & 15, kg = lane >> 4;
    int rowc = min(m0 + m, M-1);

    f4 acc[8];
    #pragma unroll
    for (int j = 0; j < 8; ++j) acc[j] = (f4)0.0f;

    // phase 0: neighbor-mean term (f16 rows)
    #pragma unroll
    for (int kt = 0; kt < 4; ++kt){
        h8 nf = *(const h8*)(A0 + (size_t)rowc*128 + kt*32 + kg*8);
        #pragma unroll
        for (int j = 0; j < 8; ++j){
            h8 wf = shB[(kt*8 + j)*64 + lane];
            acc[j] = __builtin_amdgcn_mfma_f32_16x16x32_f16(wf, nf, acc[j], 0, 0, 0);
        }
    }
    // phase 1: self term (f32 rows, convert in-register)
    #pragma unroll
    for (int kt = 0; kt < 4; ++kt){
        const float* xr = X + (size_t)rowc*128 + kt*32 + kg*8;
        f4 xa = *(const f4*)(xr);
        f4 xb = *(const f4*)(xr + 4);
        h8 nf;
        nf[0]=(_Float16)xa[0]; nf[1]=(_Float16)xa[1]; nf[2]=(_Float16)xa[2]; nf[3]=(_Float16)xa[3];
        nf[4]=(_Float16)xb[0]; nf[5]=(_Float16)xb[1]; nf[6]=(_Float16)xb[2]; nf[7]=(_Float16)xb[3];
        #pragma unroll
        for (int j = 0; j < 8; ++j){
            h8 wf = shB[2048 + (kt*8 + j)*64 + lane];
            acc[j] = __builtin_amdgcn_mfma_f32_16x16x32_f16(wf, nf, acc[j], 0, 0, 0);
        }
    }

    unsigned hreg[16];
    #pragma unroll
    for (int j = 0; j < 8; ++j){
        f4 bb = *(const f4*)(bias1 + j*16 + kg*4);
        float v0 = acc[j][0] + bb[0]; v0 = v0 > 0.f ? v0 : 0.f;
        float v1 = acc[j][1] + bb[1]; v1 = v1 > 0.f ? v1 : 0.f;
        float v2 = acc[j][2] + bb[2]; v2 = v2 > 0.f ? v2 : 0.f;
        float v3 = acc[j][3] + bb[3]; v3 = v3 > 0.f ? v3 : 0.f;
        hreg[2*j]   = packh2(v0, v1);
        hreg[2*j+1] = packh2(v2, v3);
    }

    f4 accP[4], accQ[4];
    #pragma unroll
    for (int j = 0; j < 4; ++j){ accP[j] = (f4)0.0f; accQ[j] = (f4)0.0f; }

    int srcA = ((kg & 1) * 2) * 16 + m;
    int srcB = srcA + 16;
    bool hi = (kg >> 1) & 1;

    #pragma unroll
    for (int kt = 0; kt < 4; ++kt){
        unsigned sA0 = (unsigned)__shfl((int)hreg[4*kt+0], srcA, 64);
        unsigned sA1 = (unsigned)__shfl((int)hreg[4*kt+1], srcA, 64);
        unsigned sA2 = (unsigned)__shfl((int)hreg[4*kt+2], srcA, 64);
        unsigned sA3 = (unsigned)__shfl((int)hreg[4*kt+3], srcA, 64);
        unsigned sB0 = (unsigned)__shfl((int)hreg[4*kt+0], srcB, 64);
        unsigned sB1 = (unsigned)__shfl((int)hreg[4*kt+1], srcB, 64);
        unsigned sB2 = (unsigned)__shfl((int)hreg[4*kt+2], srcB, 64);
        unsigned sB3 = (unsigned)__shfl((int)hreg[4*kt+3], srcB, 64);
        u4 u;
        u[0] = hi ? sA2 : sA0;
        u[1] = hi ? sA3 : sA1;
        u[2] = hi ? sB2 : sB0;
        u[3] = hi ? sB3 : sB1;
        h8 hf = __builtin_bit_cast(h8, u);
        #pragma unroll
        for (int j2 = 0; j2 < 4; ++j2){
            accP[j2] = __builtin_amdgcn_mfma_f32_16x16x32_f16(W2l[(kt*4 + j2)*64 + lane], hf, accP[j2], 0, 0, 0);
            accQ[j2] = __builtin_amdgcn_mfma_f32_16x16x32_f16(W2r[(kt*4 + j2)*64 + lane], hf, accQ[j2], 0, 0, 0);
        }
    }

    int node = m0 + m;
    if (node < M){
        #pragma unroll
        for (int j2 = 0; j2 < 4; ++j2){
            int f = j2*16 + kg*4;
            int p8 = __builtin_amdgcn_cvt_pk_fp8_f32(accP[j2][0], accP[j2][1], 0, false);
            p8     = __builtin_amdgcn_cvt_pk_fp8_f32(accP[j2][2], accP[j2][3], p8, true);
            P8[(size_t)node*16 + j2*4 + kg] = (unsigned)p8;
            f4 bb2 = *(const f4*)(bias2 + f);
            uint2 qp;
            qp.x = packh2(accQ[j2][0] + bb2[0], accQ[j2][1] + bb2[1]);
            qp.y = packh2(accQ[j2][2] + bb2[2], accQ[j2][3] + bb2[3]);
            Qh[(size_t)node*16 + j2*4 + kg] = qp;
        }
    }
}

// ---------------- aggregation 2: out = Qh + mean-gather(P8); 16 lanes per node, unroll-8 ----------------
__global__ void k_agg2f(const int* __restrict__ row_start, const int* __restrict__ csr,
                        const unsigned* __restrict__ p8, const uint2* __restrict__ Qh,
                        float* __restrict__ out, int n){
    int node = (int)((blockIdx.x*(unsigned)blockDim.x + threadIdx.x) >> 4);
    int c = threadIdx.x & 15;
    if (node >= n) return;
    int base = row_start[node], end = row_start[node+1];
    int deg = end - base;
    f2 a0={0.f,0.f}, a1={0.f,0.f}, b0={0.f,0.f}, b1={0.f,0.f};
    f2 c0={0.f,0.f}, c1={0.f,0.f}, d0={0.f,0.f}, d1={0.f,0.f};
    int i = base;
    for (; i + 7 < end; i += 8){
        int e0 = csr[i],   e1 = csr[i+1], e2 = csr[i+2], e3 = csr[i+3];
        int e4 = csr[i+4], e5 = csr[i+5], e6 = csr[i+6], e7 = csr[i+7];
        unsigned v0 = p8[(size_t)e0*16 + c];
        unsigned v1 = p8[(size_t)e1*16 + c];
        unsigned v2 = p8[(size_t)e2*16 + c];
        unsigned v3 = p8[(size_t)e3*16 + c];
        unsigned v4 = p8[(size_t)e4*16 + c];
        unsigned v5 = p8[(size_t)e5*16 + c];
        unsigned v6 = p8[(size_t)e6*16 + c];
        unsigned v7 = p8[(size_t)e7*16 + c];
        a0 += __builtin_amdgcn_cvt_pk_f32_fp8(v0, false);
        a1 += __builtin_amdgcn_cvt_pk_f32_fp8(v0, true);
        b0 += __builtin_amdgcn_cvt_pk_f32_fp8(v1, false);
        b1 += __builtin_amdgcn_cvt_pk_f32_fp8(v1, true);
        c0 += __builtin_amdgcn_cvt_pk_f32_fp8(v2, false);
        c1 += __builtin_amdgcn_cvt_pk_f32_fp8(v2, true);
        d0 += __builtin_amdgcn_cvt_pk_f32_fp8(v3, false);
        d1 += __builtin_amdgcn_cvt_pk_f32_fp8(v3, true);
        a0 += __builtin_amdgcn_cvt_pk_f32_fp8(v4, false);
        a1 += __builtin_amdgcn_cvt_pk_f32_fp8(v4, true);
        b0 += __builtin_amdgcn_cvt_pk_f32_fp8(v5, false);
        b1 += __builtin_amdgcn_cvt_pk_f32_fp8(v5, true);
        c0 += __builtin_amdgcn_cvt_pk_f32_fp8(v6, false);
        c1 += __builtin_amdgcn_cvt_pk_f32_fp8(v6, true);
        d0 += __builtin_amdgcn_cvt_pk_f32_fp8(v7, false);
        d1 += __builtin_amdgcn_cvt_pk_f32_fp8(v7, true);
    }
    for (; i + 3 < end; i += 4){
        int e0 = csr[i], e1 = csr[i+1], e2 = csr[i+2], e3 = csr[i+3];
        unsigned v0 = p8[(size_t)e0*16 + c];
        unsigned v1 = p8[(size_t)e1*16 + c];
        unsigned v2 = p8[(size_t)e2*16 + c];
        unsigned v3 = p8[(size_t)e3*16 + c];
        a0 += __builtin_amdgcn_cvt_pk_f32_fp8(v0, false);
        a1 += __builtin_amdgcn_cvt_pk_f32_fp8(v0, true);
        b0 += __builtin_amdgcn_cvt_pk_f32_fp8(v1, false);
        b1 += __builtin_amdgcn_cvt_pk_f32_fp8(v1, true);
        c0 += __builtin_amdgcn_cvt_pk_f32_fp8(v2, false);
        c1 += __builtin_amdgcn_cvt_pk_f32_fp8(v2, true);
        d0 += __builtin_amdgcn_cvt_pk_f32_fp8(v3, false);
        d1 += __builtin_amdgcn_cvt_pk_f32_fp8(v3, true);
    }
    for (; i < end; ++i){
        int e = csr[i];
        unsigned v = p8[(size_t)e*16 + c];
        a0 += __builtin_amdgcn_cvt_pk_f32_fp8(v, false);
        a1 += __builtin_amdgcn_cvt_pk_f32_fp8(v, true);
    }
    a0 += b0 + c0 + d0;
    a1 += b1 + c1 + d1;
    float sc = 1.0f / (float)max(deg, 1);
    uint2 qh = Qh[(size_t)node*16 + c];
    f4 o;
    o[0] = a0[0]*sc + h2lo(qh.x);
    o[1] = a0[1]*sc + h2hi(qh.x);
    o[2] = a1[0]*sc + h2lo(qh.y);
    o[3] = a1[1]*sc + h2hi(qh.y);
    *(f4*)(out + (size_t)node*64 + 4*c) = o;
}

extern "C" void kernel_launch(void* const* d_in, const int* in_sizes, int n_in,
                              void* d_out, int out_size, void* d_ws, size_t ws_size,
                              hipStream_t stream) {
    const float* x   = (const float*)d_in[0];
    const int*   ei  = (const int*)d_in[1];
    const float* Wl1 = (const float*)d_in[2];
    const float* bl1 = (const float*)d_in[3];
    const float* Wr1 = (const float*)d_in[4];
    const float* Wl2 = (const float*)d_in[5];
    const float* bl2 = (const float*)d_in[6];
    const float* Wr2 = (const float*)d_in[7];

    const int N = in_sizes[0] / IN_C;
    const int E = in_sizes[1] / 2;
    const int* src = ei;
    const int* dst = ei + E;

    const int NBLK = (E + EPB - 1) / EPB;
    const int n_s  = NBUCK * NBLK;

    char* w = (char*)d_ws;
    size_t off = 0;
    auto alloc = [&](size_t bytes) -> char* {
        char* p = w + off;
        off = (off + bytes + 255) & ~(size_t)255;
        return p;
    };
    int* histT      = (int*)alloc((size_t)n_s*4);
    int* tmp        = (int*)alloc((size_t)n_s*4);
    int* bsum       = (int*)alloc(4096);
    unsigned* sorted= (unsigned*)alloc((size_t)E*4);
    int* csr        = (int*)alloc((size_t)E*4);
    int* row_start  = (int*)alloc((size_t)(N+1)*4);
    unsigned* x8    = (unsigned*)alloc((size_t)N*IN_C);
    _Float16* m1h   = (_Float16*)alloc((size_t)N*IN_C*2);
    unsigned* p8    = (unsigned*)alloc((size_t)N*OUT_C);
    unsigned* qh    = (unsigned*)alloc((size_t)N*OUT_C*2);
    _Float16* wl1p  = (_Float16*)alloc(4*8*64*8*2);
    _Float16* wr1p  = (_Float16*)alloc(4*8*64*8*2);
    _Float16* wl2p  = (_Float16*)alloc(4*4*64*8*2);
    _Float16* wr2p  = (_Float16*)alloc(4*4*64*8*2);

    const int SB = (n_s + 255) / 256;
    const int n8 = N*IN_C/8;
    const int CVB = (n8 + 255)/256;

    k_front  <<<NBLK + 24 + CVB, 256, 0, stream>>>(dst, E, NBLK, histT,
                                                   x, (uint2*)x8, n8,
                                                   Wl1, Wr1, Wl2, Wr2, wl1p, wr1p, wl2p, wr2p);
    k_scanA  <<<SB, 256, 0, stream>>>(histT, tmp, bsum, n_s);
    k_scanB  <<<1, 1024, 0, stream>>>(bsum, SB);
    k_scatter<<<NBLK, 256, 0, stream>>>(src, dst, E, tmp, bsum, NBLK, sorted);
    k_csr    <<<NBUCK, 512, 0, stream>>>(sorted, tmp, bsum, NBLK, E, N, csr, row_start);

    const int AB = (N + 15) / 16;    // 16 lanes per node, 16 nodes per block
    k_agg1<<<AB, 256, 0, stream>>>(row_start, csr, (const uint2*)x8, (unsigned*)m1h, N);

    const int GB2 = (N + 127)/128;   // 512-thread blocks, 128 nodes each
    k_gemm_fused<<<GB2, 512, 0, stream>>>(m1h, x, (const h8*)wl1p, (const h8*)wr1p, bl1,
                                          (const h8*)wl2p, (const h8*)wr2p, bl2,
                                          p8, (uint2*)qh, N);

    k_agg2f<<<AB, 256, 0, stream>>>(row_start, csr, p8, (const uint2*)qh, (float*)d_out, N);
}